// Round 11
// baseline (212.281 us; speedup 1.0000x reference)
//
#include <hip/hip_runtime.h>
#include <math.h>

#define HW 262144          // 512*512
#define TOTAL 6291456      // 24*HW
#define PI_F 3.14159265358979323846f
#define NBIN 1024
#define PIDX(i) ((i) + ((i) >> 3))

// ---------------- ws layout (bytes) ----------------
// [0, 4096)           float  P[1024]         params
// [4096, 20480)       unsigned slots[4096]   pair-arrays + small state
// [20480, 53248)      unsigned hist[8*1024]
// [540672, 606208)    uint2  list[8*1024]
// [1048576, +32MB)    float2 bufC[16*HW]     packed FFT buffer (im = 2b: ch0+i*ch1, 2b+1: ch2)

// Params float offsets
#define PF_GATE 0
#define PF_WB 64
#define PF_GAMMA 88
#define PF_Y 96
#define PF_OMEGA 104
#define PF_ALPHA 112
#define PF_TC 120
#define PF_TSC 184
#define PF_RATE 192
#define PF_FG 200
#define PF_A 208
#define PF_WBM 256
#define PF_WBA 264
#define PF_GM 272
#define PF_GA 280
#define PF_SM 288
#define PF_SA 296
#define PF_FM 304
#define PF_FA 312
#define PF_CM 320
#define PF_CA 328
#define PF_TM 336
#define PF_TA 344
#define PF_LINE 360   // 8 ints
#define PF_TCS 368    // tc[k]*tsc, 8*8
#define PF_TPRE 432   // prefix sums, 8*8
#define PF_IA 496     // 1/a, 24

// quantity indices for min/max pair arrays: q*64 + s (min), q*64+32+s (max), s=0..31
#define QX(b,c) ((b)*3+(c))
#define QS 24
#define QJ 25
#define QC 26
#define QFIN 27
#define SL_LCOUNT 1792
#define SL_BINSTAR 1920
#define SL_RNEED 1928
#define SL_SUMA2 2048   // float[24][32]

struct GK { float w[13]; };

__device__ __forceinline__ void waveFence(){ __builtin_amdgcn_wave_barrier(); }

__device__ __forceinline__ unsigned fkey(float f){
    unsigned u = __float_as_uint(f);
    return (u & 0x80000000u) ? ~u : (u | 0x80000000u);
}
__device__ __forceinline__ float funkey(unsigned k){
    return (k & 0x80000000u) ? __uint_as_float(k & 0x7FFFFFFFu) : __uint_as_float(~k);
}

// block min/max reduce over nw waves -> one atomic pair, slot = blockIdx&31. ldsw size >= 2*nw.
__device__ __forceinline__ void blockRedPairN(unsigned kmn, unsigned kmx, int q,
                                              unsigned* slots, unsigned* ldsw, int nw){
    #pragma unroll
    for (int o = 32; o > 0; o >>= 1){
        kmn = min(kmn, __shfl_down(kmn, o));
        kmx = max(kmx, __shfl_down(kmx, o));
    }
    int w = threadIdx.x >> 6;
    if ((threadIdx.x & 63) == 0){ ldsw[w] = kmn; ldsw[nw + w] = kmx; }
    __syncthreads();
    if (threadIdx.x == 0){
        unsigned mn = ldsw[0], mx = ldsw[nw];
        for (int i = 1; i < nw; ++i){ mn = min(mn, ldsw[i]); mx = max(mx, ldsw[nw+i]); }
        int s = blockIdx.x & 31;
        atomicMin(&slots[q*64 + s], mn);
        atomicMax(&slots[q*64 + 32 + s], mx);
    }
    __syncthreads();
}

__device__ __forceinline__ float toneF(float v, const float* tc, float tsc){
    float tn = 0.f;
    #pragma unroll
    for (int i = 0; i < 8; ++i){
        float d = v - 0.125f * (float)i;
        d = fminf(fmaxf(d, 0.f), 0.125f);
        tn += d * tc[i];
    }
    return tn * tsc;
}

// ---------------- complex helpers + radix-8 Stockham FFT (512 = 8^3) ----------------
__device__ __forceinline__ float2 cadd(float2 a, float2 b){ return make_float2(a.x+b.x, a.y+b.y); }
__device__ __forceinline__ float2 csub(float2 a, float2 b){ return make_float2(a.x-b.x, a.y-b.y); }
__device__ __forceinline__ float2 cmul(float2 a, float2 b){ return make_float2(a.x*b.x - a.y*b.y, a.x*b.y + a.y*b.x); }

template<int S>   // S=-1 fwd, S=+1 inv
__device__ __forceinline__ float2 rot90(float2 z){
    return (S < 0) ? make_float2(z.y, -z.x) : make_float2(-z.y, z.x);
}

template<int S>
__device__ __forceinline__ void fft4p(float2 a, float2 b, float2 c, float2 d,
                                      float2& X0, float2& X1, float2& X2, float2& X3){
    float2 t0 = cadd(a,c), t1 = csub(a,c), t2 = cadd(b,d), t3 = csub(b,d);
    float2 it3 = rot90<S>(t3);
    X0 = cadd(t0,t2); X2 = csub(t0,t2);
    X1 = cadd(t1,it3); X3 = csub(t1,it3);
}

template<int S>
__device__ __forceinline__ void bfly8(float2 v[8]){
    const float C = 0.70710678118654752f;
    float2 E0,E1,E2,E3,O0,O1,O2,O3;
    fft4p<S>(v[0],v[2],v[4],v[6], E0,E1,E2,E3);
    fft4p<S>(v[1],v[3],v[5],v[7], O0,O1,O2,O3);
    float2 w1 = make_float2(C, (S<0) ? -C : C);
    float2 w3 = make_float2(-C, (S<0) ? -C : C);
    float2 u1 = cmul(O1, w1);
    float2 u2 = rot90<S>(O2);
    float2 u3 = cmul(O3, w3);
    v[0]=cadd(E0,O0); v[4]=csub(E0,O0);
    v[1]=cadd(E1,u1); v[5]=csub(E1,u1);
    v[2]=cadd(E2,u2); v[6]=csub(E2,u2);
    v[3]=cadd(E3,u3); v[7]=csub(E3,u3);
}

__device__ __forceinline__ void twiddles(float2 v[8], float th){
    float sn, cs; __sincosf(th, &sn, &cs);
    float2 w1 = make_float2(cs, sn);
    float2 w = w1;
    v[1] = cmul(v[1], w1);
    #pragma unroll
    for (int r = 2; r < 8; ++r){ w = cmul(w, w1); v[r] = cmul(v[r], w); }
}

// Stockham FFT, natural in/out: v[r] = elem(lane + 64r). buf PRIVATE to this wave.
template<int S>
__device__ __forceinline__ void fft512reg(float2 v[8], float2* buf, int lane){
    bfly8<S>(v);
    #pragma unroll
    for (int q = 0; q < 8; ++q) buf[PIDX(8*lane + q)] = v[q];
    waveFence();
    #pragma unroll
    for (int r = 0; r < 8; ++r) v[r] = buf[PIDX(lane + 64*r)];
    waveFence();
    twiddles(v, (float)S * 6.2831853072f * (float)(lane & 7) * (1.0f/64.0f));
    bfly8<S>(v);
    {
        int basei = ((lane >> 3) << 6) + (lane & 7);
        #pragma unroll
        for (int q = 0; q < 8; ++q) buf[PIDX(basei + 8*q)] = v[q];
    }
    waveFence();
    #pragma unroll
    for (int r = 0; r < 8; ++r) v[r] = buf[PIDX(lane + 64*r)];
    waveFence();
    twiddles(v, (float)S * 6.2831853072f * (float)lane * (1.0f/512.0f));
    bfly8<S>(v);
}

// ---------------- setup ----------------
__global__ __launch_bounds__(256) void kSetup(
    const float* __restrict__ lat,
    const float* gw, const float* gb, const float* wbw, const float* wbb,
    const float* gaw, const float* gab, const float* shw, const float* shb,
    const float* dfw, const float* dfb, const float* ctw, const float* ctb,
    const float* tow, const float* tob, const float* ffw, const float* ffb,
    float* P, unsigned* slots, unsigned* hist)
{
    if (blockIdx.x != 0){
        int i = (blockIdx.x - 1) * 256 + threadIdx.x;
        if (i < 4096) slots[i] = (i < 1792 && (i & 63) < 32) ? 0xFFFFFFFFu : 0u;
        if (i < 8192) hist[i] = 0u;
        return;
    }
    int t = threadIdx.x;
    if (t < 192){
        int b = t / 24, o = t % 24;
        const float* L = lat + b * 256;
        const float* W; float bias; int nc, col;
        if (o < 8)      { W=gw;  bias=gb[o];     nc=8; col=o;    }
        else if (o < 11){ W=wbw; bias=wbb[o-8];  nc=3; col=o-8;  }
        else if (o==11) { W=gaw; bias=gab[0];    nc=1; col=0;    }
        else if (o==12) { W=shw; bias=shb[0];    nc=1; col=0;    }
        else if (o==13) { W=dfw; bias=dfb[0];    nc=1; col=0;    }
        else if (o==14) { W=ctw; bias=ctb[0];    nc=1; col=0;    }
        else if (o<23)  { W=tow; bias=tob[o-15]; nc=8; col=o-15; }
        else            { W=ffw; bias=ffb[0];    nc=1; col=0;    }
        float acc = bias;
        for (int d = 0; d < 256; ++d) acc += L[d] * W[d*nc + col];
        float t01 = tanhf(acc) * 0.5f + 0.5f;
        if (o < 8){ float v = t01*0.99f + 0.01f; P[PF_GATE + b*8 + o] = v; if (o==7) P[PF_FG + b] = v; }
        else if (o < 11){ P[PF_WB + b*3 + (o-8)] = expf(t01 - 0.5f); }
        else if (o==11){ float lg = logf(2.5f); P[PF_GAMMA + b] = expf(t01*(2.f*lg) - lg); }
        else if (o==12){ P[PF_Y + b] = t01*0.9f + 0.1f; }
        else if (o==13){ P[PF_OMEGA + b] = t01*0.9f + 0.1f; }
        else if (o==14){ P[PF_ALPHA + b] = tanhf(acc); }
        else if (o<23){ P[PF_TC + b*8 + (o-15)] = t01*1.5f + 0.5f; }
        else { P[PF_RATE + b] = t01*0.7f + 0.1f; }
    }
    __syncthreads();
    if (t < 8){
        int b = t;
        float w0=P[PF_WB+b*3], w1=P[PF_WB+b*3+1], w2=P[PF_WB+b*3+2];
        float cs = 1.0f / (1e-5f + 0.27f*w0 + 0.67f*w1 + 0.06f*w2);
        P[PF_WB+b*3] = cs*w0; P[PF_WB+b*3+1] = cs*w1; P[PF_WB+b*3+2] = cs*w2;
        float ts = 0.f;
        for (int i = 0; i < 8; ++i) ts += P[PF_TC + b*8 + i];
        float tsc = 8.0f / (ts + 1e-30f);
        P[PF_TSC + b] = tsc;
        float acc = 0.f;
        for (int k = 0; k < 8; ++k){
            float tck = P[PF_TC + b*8 + k] * tsc;
            P[PF_TCS + b*8 + k] = tck;
            P[PF_TPRE + b*8 + k] = acc;
            acc += tck * 0.125f;
        }
        int bs = (b + 4) & 7; // fftshift batch roll
        ((int*)(P + PF_LINE))[b] = (int)floorf(sqrtf(262144.0f * P[PF_RATE + bs]) * 0.5f);
    }
}

// ---------------- x min/max per (b,c) + dark histogram ----------------
__global__ __launch_bounds__(256) void kMinmaxHist(const float* __restrict__ x, unsigned* slots, unsigned* hist){
    __shared__ unsigned h[NBIN];
    __shared__ unsigned lds8[8];
    int b = blockIdx.x >> 7;
    int blk = blockIdx.x & 127;
    for (int i = threadIdx.x; i < NBIN; i += 256) h[i] = 0u;
    __syncthreads();
    size_t xb = (size_t)b*3*HW;
    int p0 = (((blk<<1)    )*256 + threadIdx.x) << 2;
    int p1 = (((blk<<1) + 1)*256 + threadIdx.x) << 2;
    float4 u0 = *(const float4*)(x + xb + p0);
    float4 u1 = *(const float4*)(x + xb + HW + p0);
    float4 u2 = *(const float4*)(x + xb + 2*HW + p0);
    float4 w0 = *(const float4*)(x + xb + p1);
    float4 w1 = *(const float4*)(x + xb + HW + p1);
    float4 w2 = *(const float4*)(x + xb + 2*HW + p1);
    float a0[8] = {u0.x,u0.y,u0.z,u0.w, w0.x,w0.y,w0.z,w0.w};
    float a1[8] = {u1.x,u1.y,u1.z,u1.w, w1.x,w1.y,w1.z,w1.w};
    float a2[8] = {u2.x,u2.y,u2.z,u2.w, w2.x,w2.y,w2.z,w2.w};
    float mn0=1e30f,mx0=-1e30f,mn1=1e30f,mx1=-1e30f,mn2=1e30f,mx2=-1e30f;
    #pragma unroll
    for (int e = 0; e < 8; ++e){
        float dark = fminf(a0[e], fminf(a1[e], a2[e]));
        atomicAdd(&h[min(NBIN-1, (int)(dark * (float)NBIN))], 1u);
        mn0 = fminf(mn0, a0[e]); mx0 = fmaxf(mx0, a0[e]);
        mn1 = fminf(mn1, a1[e]); mx1 = fmaxf(mx1, a1[e]);
        mn2 = fminf(mn2, a2[e]); mx2 = fmaxf(mx2, a2[e]);
    }
    __syncthreads();
    for (int i = threadIdx.x; i < NBIN; i += 256){
        unsigned c = h[i];
        if (c) atomicAdd(&hist[b*NBIN + i], c);
    }
    blockRedPairN(fkey(mn0), fkey(mx0), QX(b,0), slots, lds8, 4);
    blockRedPairN(fkey(mn1), fkey(mx1), QX(b,1), slots, lds8, 4);
    blockRedPairN(fkey(mn2), fkey(mx2), QX(b,2), slots, lds8, 4);
}

// ---------------- descending scan of histogram -> threshold bin ----------------
__global__ __launch_bounds__(256) void kScanHist(const unsigned* __restrict__ hist, unsigned* slots){
    int b = blockIdx.x, t = threadIdx.x;
    __shared__ unsigned wtot[4];
    __shared__ int doneS;
    if (t == 0) doneS = 0;
    __syncthreads();
    unsigned total = 0;
    for (int c0 = 0; c0 < NBIN; c0 += 256){
        int binIdx = NBIN-1 - (c0 + t);
        unsigned cnt = hist[b*NBIN + binIdx];
        unsigned v = cnt;
        #pragma unroll
        for (int off = 1; off < 64; off <<= 1){
            unsigned u = __shfl_up(v, off);
            if ((t & 63) >= off) v += u;
        }
        if ((t & 63) == 63) wtot[t >> 6] = v;
        __syncthreads();
        unsigned wofs = 0;
        for (int w = 0; w < (t >> 6); ++w) wofs += wtot[w];
        unsigned incl = total + wofs + v;
        unsigned excl = incl - cnt;
        if (incl >= 261u && excl < 261u){
            slots[SL_BINSTAR + b] = (unsigned)binIdx;
            slots[SL_RNEED + b]   = 261u - excl;
            doneS = 1;
        }
        __syncthreads();
        if (doneS) break;
        total += wtot[0] + wtot[1] + wtot[2] + wtot[3];
        __syncthreads();
    }
}

// ---------------- collect: block-reduced above-threshold sums + boundary list ----------------
__global__ __launch_bounds__(256) void kCollect(const float* __restrict__ x, unsigned* slots, uint2* list){
    __shared__ float wsum[3][4];
    int b = blockIdx.x >> 8;
    int tile = blockIdx.x & 255;
    size_t xb = (size_t)b*3*HW;
    int p = (tile*256 + threadIdx.x) << 2;
    float4 v0 = *(const float4*)(x + xb + p);
    float4 v1 = *(const float4*)(x + xb + HW + p);
    float4 v2 = *(const float4*)(x + xb + 2*HW + p);
    int bs = (int)slots[SL_BINSTAR + b];
    float a0[4] = {v0.x,v0.y,v0.z,v0.w};
    float a1[4] = {v1.x,v1.y,v1.z,v1.w};
    float a2[4] = {v2.x,v2.y,v2.z,v2.w};
    float s0 = 0.f, s1 = 0.f, s2 = 0.f;
    #pragma unroll
    for (int e = 0; e < 4; ++e){
        float dark = fminf(a0[e], fminf(a1[e], a2[e]));
        int bin = min(NBIN-1, (int)(dark * (float)NBIN));
        if (bin > bs){ s0 += a0[e]; s1 += a1[e]; s2 += a2[e]; }
        else if (bin == bs){
            unsigned n = atomicAdd(&slots[SL_LCOUNT + b], 1u);
            if (n < 1024u) list[(b << 10) + n] = make_uint2(__float_as_uint(dark), (unsigned)(p + e));
        }
    }
    #pragma unroll
    for (int o = 32; o > 0; o >>= 1){
        s0 += __shfl_down(s0, o); s1 += __shfl_down(s1, o); s2 += __shfl_down(s2, o);
    }
    int w = threadIdx.x >> 6;
    if ((threadIdx.x & 63) == 0){ wsum[0][w] = s0; wsum[1][w] = s1; wsum[2][w] = s2; }
    __syncthreads();
    if (threadIdx.x == 0){
        float t0 = wsum[0][0]+wsum[0][1]+wsum[0][2]+wsum[0][3];
        float t1 = wsum[1][0]+wsum[1][1]+wsum[1][2]+wsum[1][3];
        float t2 = wsum[2][0]+wsum[2][1]+wsum[2][2]+wsum[2][3];
        float* F = (float*)(slots + SL_SUMA2);
        int sl = blockIdx.x & 31;
        atomicAdd(&F[(b*3+0)*32 + sl], t0);
        atomicAdd(&F[(b*3+1)*32 + sl], t1);
        atomicAdd(&F[(b*3+2)*32 + sl], t2);
    }
}

// ---------------- finish atmospheric light: wave-parallel top-r selection ----------------
__global__ void kSelect(const float* __restrict__ x, uint2* list, unsigned* slots, float* P){
    __shared__ unsigned pid[262];
    __shared__ char taken[1024];
    int b = blockIdx.x, t = threadIdx.x;  // 64 threads
    int n = (int)min(slots[SL_LCOUNT + b], 1024u);
    int r = (int)slots[SL_RNEED + b];
    if (r > n) r = n;
    const uint2* L = &list[b << 10];
    for (int i = t; i < n; i += 64) taken[i] = 0;
    __syncthreads();
    for (int it = 0; it < r; ++it){
        unsigned long long bk = 0ull; int bp = -1;
        for (int i = t; i < n; i += 64){
            if (taken[i]) continue;
            uint2 e = L[i];
            unsigned long long key = ((unsigned long long)e.x << 32) | e.y;
            if (key > bk){ bk = key; bp = i; }
        }
        #pragma unroll
        for (int o = 32; o > 0; o >>= 1){
            unsigned long long ok = __shfl_down(bk, o);
            int op = __shfl_down(bp, o);
            if (ok > bk){ bk = ok; bp = op; }
        }
        bp = __shfl(bp, 0);
        if (t == 0){ pid[it] = L[bp].y; taken[bp] = 1; }
        __syncthreads();
    }
    float s0 = 0.f, s1 = 0.f, s2 = 0.f;
    size_t xb = (size_t)b*3*HW;
    for (int i = t; i < r; i += 64){
        unsigned id = pid[i];
        s0 += x[xb + id]; s1 += x[xb + HW + id]; s2 += x[xb + 2*HW + id];
    }
    #pragma unroll
    for (int o = 32; o > 0; o >>= 1){
        s0 += __shfl_down(s0, o); s1 += __shfl_down(s1, o); s2 += __shfl_down(s2, o);
    }
    if (t == 0){
        const float* F = (const float*)(slots + SL_SUMA2);
        float f0 = 0.f, f1 = 0.f, f2 = 0.f;
        for (int k = 0; k < 32; ++k){
            f0 += F[(b*3+0)*32 + k];
            f1 += F[(b*3+1)*32 + k];
            f2 += F[(b*3+2)*32 + k];
        }
        float A0 = (s0 + f0) / 262.0f, A1 = (s1 + f1) / 262.0f, A2 = (s2 + f2) / 262.0f;
        P[PF_A + b*3+0] = A0; P[PF_A + b*3+1] = A1; P[PF_A + b*3+2] = A2;
        P[PF_IA + b*3+0] = 1.0f/A0; P[PF_IA + b*3+1] = 1.0f/A1; P[PF_IA + b*3+2] = 1.0f/A2;
    }
}

// ---------------- fused gaussian blur (separable, reflect, 64x64 tile) ----------------
__global__ __launch_bounds__(256) void kBlur(const float* __restrict__ x, float* __restrict__ blurOut,
                                             const float* __restrict__ P, unsigned* slots, GK gk){
    __shared__ float tile[76][80];
    __shared__ float hbuf[76][68];
    __shared__ unsigned lds8[8];
    int img = blockIdx.x >> 6;
    int tid = blockIdx.x & 63;
    int tr0 = (tid >> 3) << 6;
    int tc0 = (tid & 7) << 6;
    size_t ib = (size_t)img * HW;
    int t = threadIdx.x;
    for (int l = t; l < 76*76; l += 256){
        int r = l / 76, c = l - r*76;
        int gr = tr0 + r - 6; gr = (gr < 0) ? -gr : ((gr > 511) ? 1022 - gr : gr);
        int gc = tc0 + c - 6; gc = (gc < 0) ? -gc : ((gc > 511) ? 1022 - gc : gc);
        tile[r][c] = x[ib + ((size_t)gr << 9) + gc];
    }
    __syncthreads();
    for (int l = t; l < 76*64; l += 256){
        int r = l >> 6, c = l & 63;
        float acc = 0.f;
        #pragma unroll
        for (int k = 0; k < 13; ++k) acc += gk.w[k] * tile[r][c + k];
        hbuf[r][c] = acc;
    }
    __syncthreads();
    float yb = P[PF_Y + img/3];
    unsigned kmn = 0xFFFFFFFFu, kmx = 0u;
    for (int l = t; l < 64*64; l += 256){
        int r = l >> 6, c = l & 63;
        float acc = 0.f;
        #pragma unroll
        for (int k = 0; k < 13; ++k) acc += gk.w[k] * hbuf[r + k][c];
        blurOut[ib + ((size_t)(tr0 + r) << 9) + tc0 + c] = acc;
        float xv = tile[r + 6][c + 6];
        float s = xv + yb * (xv - acc);
        unsigned key = fkey(s);
        kmn = min(kmn, key); kmx = max(kmx, key);
    }
    blockRedPairN(kmn, kmx, QS, slots, lds8, 4);
}

// ---------------- fused: fwd row FFT, 4 rows/block, 6 FFT units + JC min/max ----------------
// units 0-3: ch0+i*ch1 per row; units 4-5: ch2 row-pair packed + Hermitian unpack.
// LDS: xs[4][3][512] (24KB) aliases Stockham buf6 (27.2KB)
__global__ __launch_bounds__(384) void kFftRowFwdJC(const float* __restrict__ x, float2* __restrict__ bc,
                                                    const float* __restrict__ P, unsigned* slots){
    __shared__ float2 buf6[6][580];
    __shared__ unsigned lds12[12];
    float (*xs)[3][512] = reinterpret_cast<float(*)[3][512]>(&buf6[0][0]);
    int b = blockIdx.x >> 7;
    int rq = blockIdx.x & 127;
    int t = threadIdx.x;
    #pragma unroll
    for (int k = 0; k < 4; ++k){
        int l = t + k*384;             // 0..1535
        int rc = l >> 7;               // 0..11
        int idx = (l & 127) << 2;
        int row = rc / 3, ch = rc - row*3;
        float4 z = *(const float4*)(x + (size_t)(3*b + ch)*HW + ((size_t)(4*rq + row) << 9) + idx);
        *(float4*)&xs[row][ch][idx] = z;
    }
    __syncthreads();
    // JC min/max over 4 rows (512 float4-groups, 2 iterations)
    {
        float ia0 = P[PF_IA+b*3], ia1 = P[PF_IA+b*3+1], ia2 = P[PF_IA+b*3+2];
        float a0 = P[PF_A+b*3],  a1 = P[PF_A+b*3+1],  a2 = P[PF_A+b*3+2];
        float om = P[PF_OMEGA+b], al = P[PF_ALPHA+b];
        float jmn = 1e30f, jmx = -1e30f, cmn = 1e30f, cmx = -1e30f;
        for (int it = 0; it < 2; ++it){
            int g = t + it*384;
            if (g >= 512) break;
            int row = g >> 7, c4 = (g & 127) << 2;
            float4 xv0 = *(float4*)&xs[row][0][c4];
            float4 xv1 = *(float4*)&xs[row][1][c4];
            float4 xv2 = *(float4*)&xs[row][2][c4];
            float A0[4]={xv0.x,xv0.y,xv0.z,xv0.w}, A1[4]={xv1.x,xv1.y,xv1.z,xv1.w}, A2[4]={xv2.x,xv2.y,xv2.z,xv2.w};
            #pragma unroll
            for (int e = 0; e < 4; ++e){
                float x0 = A0[e], x1 = A1[e], x2 = A2[e];
                float dr = fminf(x0*ia0, fminf(x1*ia1, x2*ia2));
                float T = fmaxf(1.0f - om*dr, 0.01f);
                float rT = 1.0f / T;
                float j0 = (x0-a0)*rT + a0, j1 = (x1-a1)*rT + a1, j2 = (x2-a2)*rT + a2;
                float lum = fminf(fmaxf(0.27f*x0 + 0.67f*x1 + 0.06f*x2, 0.f), 1.f);
                float clum = -__cosf(PI_F*lum)*0.5f + 0.5f;
                float alx = (1.f - al) + al * (clum / (lum + 1e-6f));
                float c0 = x0*alx, c1 = x1*alx, c2 = x2*alx;
                jmn = fminf(jmn, fminf(j0, fminf(j1, j2))); jmx = fmaxf(jmx, fmaxf(j0, fmaxf(j1, j2)));
                cmn = fminf(cmn, fminf(c0, fminf(c1, c2))); cmx = fmaxf(cmx, fmaxf(c0, fmaxf(c1, c2)));
            }
        }
        blockRedPairN(fkey(jmn), fkey(jmx), QJ, slots, lds12, 6);
        blockRedPairN(fkey(cmn), fkey(cmx), QC, slots, lds12, 6);
    }
    // FFT phase: 6 units
    int u = t >> 6, lane = t & 63;
    float2 v[8];
    if (u < 4){
        #pragma unroll
        for (int r = 0; r < 8; ++r){
            int i = lane + 64*r;
            v[r] = make_float2(xs[u][0][i] * (1.0f/512.0f), xs[u][1][i] * (1.0f/512.0f));
        }
    } else {
        int pr = (u - 4) * 2;
        #pragma unroll
        for (int r = 0; r < 8; ++r){
            int i = lane + 64*r;
            v[r] = make_float2(xs[pr][2][i] * (1.0f/512.0f), xs[pr+1][2][i] * (1.0f/512.0f));
        }
    }
    __syncthreads();   // xs reads done before buf6 overwrites (cross-wave alias)
    fft512reg<-1>(v, buf6[u], lane);
    if (u < 4){
        size_t ob = (size_t)(2*b)*HW + ((size_t)(4*rq + u) << 9);
        #pragma unroll
        for (int q = 0; q < 8; ++q) bc[ob + lane + 64*q] = v[q];
    } else {
        // Hermitian unpack: S_r = 0.5(Z(f)+conj(Z(-f))), S_{r+1} = -0.5i(Z(f)-conj(Z(-f)))
        float2* B = buf6[u];
        #pragma unroll
        for (int q = 0; q < 8; ++q) B[PIDX(lane + 64*q)] = v[q];
        waveFence();
        int pr = (u - 4) * 2;
        size_t o0 = (size_t)(2*b+1)*HW + ((size_t)(4*rq + pr) << 9);
        size_t o1 = o0 + 512;
        #pragma unroll
        for (int q = 0; q < 8; ++q){
            int f = lane + 64*q;
            float2 Z = v[q];
            float2 M = B[PIDX((512 - f) & 511)];
            bc[o0 + f] = make_float2(0.5f*(Z.x + M.x),  0.5f*(Z.y - M.y));
            bc[o1 + f] = make_float2(0.5f*(Z.y + M.y), -0.5f*(Z.x - M.x));
        }
    }
}

// ---------------- FFT column pass: 8-col coalesced tile, fwd + mask + inv (16 packed images) ----------------
__global__ __launch_bounds__(256) void kFftColMid(float2* __restrict__ bc, const int* __restrict__ lineS){
    int img  = blockIdx.x >> 6;
    int tile = blockIdx.x & 63;
    int c0 = tile << 3;
    int line = lineS[img >> 1];
    if (c0 >= line && c0 + 8 <= 512 - line) return;  // tile fully unmasked: identity
    __shared__ float2 cb[8][580];
    int t = threadIdx.x;
    size_t ibase = (size_t)img*HW + c0;
    for (int k = 0; k < 16; ++k){
        int idx = (k << 8) + t;
        int row = idx >> 3, col = idx & 7;
        float2 z = bc[ibase + ((size_t)row << 9) + col];
        cb[col][PIDX(row)] = make_float2(z.x * (1.0f/512.0f), z.y * (1.0f/512.0f));
    }
    __syncthreads();
    int lane = t & 63, u = t >> 6;
    #pragma unroll
    for (int h = 0; h < 2; ++h){
        int col = (h << 2) + u;          // disjoint col sets per h -> no cross-wave hazard
        int cc = c0 + col;
        bool colM = (cc < line) || (cc >= 512 - line);
        float2 v[8];
        #pragma unroll
        for (int r = 0; r < 8; ++r) v[r] = cb[col][PIDX(lane + 64*r)];
        waveFence();
        fft512reg<-1>(v, cb[col], lane);
        if (colM){
            #pragma unroll
            for (int q = 0; q < 8; ++q){
                int f = lane + (q << 6);
                if (f < line || f >= 512 - line) v[q] = make_float2(0.f, 0.f);
            }
        }
        waveFence();
        fft512reg<+1>(v, cb[col], lane);
        #pragma unroll
        for (int q = 0; q < 8; ++q) cb[col][PIDX(lane + 64*q)] = v[q];
        waveFence();
    }
    __syncthreads();
    for (int k = 0; k < 16; ++k){
        int idx = (k << 8) + t;
        int row = idx >> 3, col = idx & 7;
        int cc = c0 + col;
        if (cc < line || cc >= 512 - line)
            bc[ibase + ((size_t)row << 9) + col] = cb[col][PIDX(row)];
    }
}

// ---------------- fused: inverse row FFT, 4 rows/block, 6 FFT units + combine ----------------
// units 0-3: ch01 per row; units 4-5: ch2 spectra of row pairs packed (Hermitian -> real).
// LDS: buf6 (27.2KB) time-shared with fbuf[4][3][512] (24KB)
__global__ __launch_bounds__(384) void kCombineFFT(const float* __restrict__ x, float* __restrict__ outb,
                                                   const float2* __restrict__ bc, const float* __restrict__ P,
                                                   unsigned* slots){
    __shared__ float2 buf6[6][580];
    __shared__ float stc[8], spre[8];
    __shared__ unsigned lds12[12];
    float (*fbuf)[3][512] = reinterpret_cast<float(*)[3][512]>(&buf6[0][0]);
    int b = blockIdx.x >> 7;
    int rq = blockIdx.x & 127;
    int t = threadIdx.x;
    if (t < 8){ stc[t] = P[PF_TCS + b*8 + t]; spre[t] = P[PF_TPRE + b*8 + t]; }
    int u = t >> 6, lane = t & 63;
    float2 v[8];
    if (u < 4){
        size_t ib = (size_t)(2*b)*HW + ((size_t)(4*rq + u) << 9);
        #pragma unroll
        for (int r = 0; r < 8; ++r) v[r] = bc[ib + lane + 64*r];
    } else {
        int pr = (u - 4) * 2;
        size_t i0 = (size_t)(2*b+1)*HW + ((size_t)(4*rq + pr) << 9);
        #pragma unroll
        for (int r = 0; r < 8; ++r){
            int i = lane + 64*r;
            float2 s0 = bc[i0 + i];
            float2 s1 = bc[i0 + 512 + i];
            v[r] = make_float2(s0.x - s1.y, s0.y + s1.x);   // S_r + i*S_{r+1}
        }
    }
    fft512reg<+1>(v, buf6[u], lane);
    __syncthreads();   // all buf6 reads done before fbuf overwrites (cross-wave alias)
    if (u < 4){
        #pragma unroll
        for (int q = 0; q < 8; ++q){
            int i = lane + 64*q;
            fbuf[u][0][i] = fabsf(v[q].x);
            fbuf[u][1][i] = fabsf(v[q].y);
        }
    } else {
        int pr = (u - 4) * 2;
        #pragma unroll
        for (int q = 0; q < 8; ++q){
            int i = lane + 64*q;
            fbuf[pr][2][i]   = fabsf(v[q].x);
            fbuf[pr+1][2][i] = fabsf(v[q].y);
        }
    }
    __syncthreads();

    float g  = P[PF_FG + b];
    float wb0=P[PF_WB+b*3], wb1=P[PF_WB+b*3+1], wb2=P[PF_WB+b*3+2];
    float gam=P[PF_GAMMA+b], yb=P[PF_Y+b], om=P[PF_OMEGA+b], al=P[PF_ALPHA+b];
    float a0=P[PF_A+b*3], a1=P[PF_A+b*3+1], a2=P[PF_A+b*3+2];
    float ia0=P[PF_IA+b*3], ia1=P[PF_IA+b*3+1], ia2=P[PF_IA+b*3+2];
    float g2=P[PF_GATE+b*8+2];
    float wbm=P[PF_WBM+b], wba=P[PF_WBA+b], gm=P[PF_GM+b], ga=P[PF_GA+b];
    float sm=P[PF_SM+b], sa=P[PF_SA+b], fm=P[PF_FM+b], fa=P[PF_FA+b];
    float cm=P[PF_CM+b], ca=P[PF_CA+b], tm=P[PF_TM+b], ta=P[PF_TA+b];
    float kadd = wba + ga + sa + fa + ca + ta;

    float mn = 1e30f, mx = -1e30f;
    for (int it = 0; it < 2; ++it){
        int gidx = t + it*384;
        if (gidx >= 512) break;
        int row = gidx >> 7, c4 = (gidx & 127) << 2;
        size_t p0 = (size_t)(3*b)*HW + ((size_t)(4*rq + row) << 9) + c4;
        float4 xv0 = *(const float4*)(x + p0);
        float4 xv1 = *(const float4*)(x + p0 + HW);
        float4 xv2 = *(const float4*)(x + p0 + 2*HW);
        float4 bv0 = *(const float4*)(outb + p0);
        float4 bv1 = *(const float4*)(outb + p0 + HW);
        float4 bv2 = *(const float4*)(outb + p0 + 2*HW);
        float4 fv0 = *(float4*)&fbuf[row][0][c4];
        float4 fv1 = *(float4*)&fbuf[row][1][c4];
        float4 fv2 = *(float4*)&fbuf[row][2][c4];
        float X0[4]={xv0.x,xv0.y,xv0.z,xv0.w}, X1[4]={xv1.x,xv1.y,xv1.z,xv1.w}, X2[4]={xv2.x,xv2.y,xv2.z,xv2.w};
        float B0[4]={bv0.x,bv0.y,bv0.z,bv0.w}, B1[4]={bv1.x,bv1.y,bv1.z,bv1.w}, B2[4]={bv2.x,bv2.y,bv2.z,bv2.w};
        float F0[4]={fv0.x,fv0.y,fv0.z,fv0.w}, F1[4]={fv1.x,fv1.y,fv1.z,fv1.w}, F2[4]={fv2.x,fv2.y,fv2.z,fv2.w};
        float O0[4], O1[4], O2[4];
        #pragma unroll
        for (int e = 0; e < 4; ++e){
            float x0 = X0[e], x1 = X1[e], x2 = X2[e];
            float dr = fminf(x0*ia0, fminf(x1*ia1, x2*ia2));
            float T = fmaxf(1.0f - om*dr, 0.01f);
            float rT = 1.0f / T;
            float lum = fminf(fmaxf(0.27f*x0 + 0.67f*x1 + 0.06f*x2, 0.f), 1.f);
            float clum = -__cosf(PI_F*lum)*0.5f + 0.5f;
            float alx = (1.f - al) + al * (clum / (lum + 1e-6f));
            #pragma unroll
            for (int ch = 0; ch < 3; ++ch){
                float xv = (ch==0)?x0:((ch==1)?x1:x2);
                float bl = (ch==0)?B0[e]:((ch==1)?B1[e]:B2[e]);
                float fv = (ch==0)?F0[e]:((ch==1)?F1[e]:F2[e]);
                float wb = (ch==0)?wb0:((ch==1)?wb1:wb2);
                float av = (ch==0)?a0:((ch==1)?a1:a2);
                float s = xv + yb*(xv - bl);
                float j = (xv - av)*rT + av;
                float ci = xv * alx;
                int k = min(7, (int)(xv * 8.0f));
                float tn = spre[k] + (xv - 0.125f*(float)k) * stc[k];
                float gp = __powf(fmaxf(xv, 1e-4f), gam);
                float sum = (wb*xv)*wbm + gp*gm + xv*g2 + s*sm + j*fm + ci*cm + tn*tm + kadd + fv*g;
                if (ch==0) O0[e]=sum; else if (ch==1) O1[e]=sum; else O2[e]=sum;
                mn = fminf(mn, sum); mx = fmaxf(mx, sum);
            }
        }
        *(float4*)(outb + p0)        = make_float4(O0[0],O0[1],O0[2],O0[3]);
        *(float4*)(outb + p0 + HW)   = make_float4(O1[0],O1[1],O1[2],O1[3]);
        *(float4*)(outb + p0 + 2*HW) = make_float4(O2[0],O2[1],O2[2],O2[3]);
    }
    blockRedPairN(fkey(mn), fkey(mx), QFIN, slots, lds12, 6);
}

// ---------------- normalization params ----------------
__global__ void kNormParams(float* P, const unsigned* __restrict__ slots){
    __shared__ float mnv[28], mxv[28];
    int t = threadIdx.x;
    if (t < 28){
        unsigned kmn = 0xFFFFFFFFu, kmx = 0u;
        for (int s = 0; s < 32; ++s){
            kmn = min(kmn, slots[t*64 + s]);
            kmx = max(kmx, slots[t*64 + 32 + s]);
        }
        mnv[t] = funkey(kmn); mxv[t] = funkey(kmx);
    }
    __syncthreads();
    if (t == 0){
        float wmin=1e30f, wmax=-1e30f, gmin=1e30f, gmax=-1e30f, tmin=1e30f, tmax=-1e30f;
        for (int b = 0; b < 8; ++b){
            float gam = P[PF_GAMMA+b];
            float tsc = P[PF_TSC+b];
            const float* tc = &P[PF_TC + b*8];
            float xbmin = 1e30f, xbmax = -1e30f;
            for (int c = 0; c < 3; ++c){
                int i = b*3 + c;
                float w = P[PF_WB + i];
                wmin = fminf(wmin, w * mnv[i]); wmax = fmaxf(wmax, w * mxv[i]);
                gmin = fminf(gmin, __powf(fmaxf(mnv[i], 1e-4f), gam));
                gmax = fmaxf(gmax, __powf(fmaxf(mxv[i], 1e-4f), gam));
                xbmin = fminf(xbmin, mnv[i]); xbmax = fmaxf(xbmax, mxv[i]);
            }
            tmin = fminf(tmin, toneF(xbmin, tc, tsc));
            tmax = fmaxf(tmax, toneF(xbmax, tc, tsc));
        }
        float smin = mnv[QS], smax = mxv[QS];
        float jmin = mnv[QJ], jmax = mxv[QJ];
        float cmin = mnv[QC], cmax = mxv[QC];
        for (int b = 0; b < 8; ++b){
            const float* G = &P[PF_GATE + b*8];
            float m;
            m = G[0]/(wmax-wmin); P[PF_WBM+b]=m; P[PF_WBA+b]=-wmin*m;
            m = G[1]/(gmax-gmin); P[PF_GM +b]=m; P[PF_GA +b]=-gmin*m;
            m = G[3]/(smax-smin); P[PF_SM +b]=m; P[PF_SA +b]=-smin*m;
            m = G[4]/(jmax-jmin); P[PF_FM +b]=m; P[PF_FA +b]=-jmin*m;
            m = G[5]/(cmax-cmin); P[PF_CM +b]=m; P[PF_CA +b]=-cmin*m;
            m = G[6]/(tmax-tmin); P[PF_TM +b]=m; P[PF_TA +b]=-tmin*m;
        }
    }
}

__global__ __launch_bounds__(256) void kFinalNorm(float* __restrict__ out, const unsigned* __restrict__ slots){
    unsigned kmn = 0xFFFFFFFFu, kmx = 0u;
    for (int s = 0; s < 32; ++s){
        kmn = min(kmn, slots[QFIN*64 + s]);
        kmx = max(kmx, slots[QFIN*64 + 32 + s]);
    }
    float mn = funkey(kmn), mx = funkey(kmx);
    float inv = 1.0f / (mx - mn);
    size_t i = ((size_t)blockIdx.x*256 + threadIdx.x) << 2;
    float4 v = *(const float4*)(out + i);
    v.x = (v.x - mn) * inv; v.y = (v.y - mn) * inv;
    v.z = (v.z - mn) * inv; v.w = (v.w - mn) * inv;
    *(float4*)(out + i) = v;
}

extern "C" void kernel_launch(void* const* d_in, const int* in_sizes, int n_in,
                              void* d_out, int out_size, void* d_ws, size_t ws_size,
                              hipStream_t stream){
    const float* x   = (const float*)d_in[0];
    const float* lat = (const float*)d_in[1];
    const float* gw  = (const float*)d_in[2];  const float* gb  = (const float*)d_in[3];
    const float* wbw = (const float*)d_in[4];  const float* wbb = (const float*)d_in[5];
    const float* gaw = (const float*)d_in[6];  const float* gab = (const float*)d_in[7];
    const float* shw = (const float*)d_in[8];  const float* shb = (const float*)d_in[9];
    const float* dfw = (const float*)d_in[10]; const float* dfb = (const float*)d_in[11];
    const float* ctw = (const float*)d_in[12]; const float* ctb = (const float*)d_in[13];
    const float* tow = (const float*)d_in[14]; const float* tob = (const float*)d_in[15];
    const float* ffw = (const float*)d_in[16]; const float* ffb = (const float*)d_in[17];
    float* out = (float*)d_out;
    char* ws = (char*)d_ws;

    float*    P     = (float*)ws;
    unsigned* slots = (unsigned*)(ws + 4096);
    unsigned* hist  = (unsigned*)(ws + 20480);
    uint2*    list  = (uint2*)(ws + 540672);
    float2*   bufC  = (float2*)(ws + 1048576);
    const int* lineS = (const int*)(P + PF_LINE);

    GK gk;
    {
        float s = 0.f;
        for (int i = 0; i < 13; ++i){ float t = (float)i - 6.f; gk.w[i] = expf(-(t*t)/8.0f); s += gk.w[i]; }
        for (int i = 0; i < 13; ++i) gk.w[i] /= s;
    }

    hipLaunchKernelGGL(kSetup,       dim3(41),   dim3(256), 0, stream, lat, gw,gb,wbw,wbb,gaw,gab,shw,shb,dfw,dfb,ctw,ctb,tow,tob,ffw,ffb, P, slots, hist);
    hipLaunchKernelGGL(kMinmaxHist,  dim3(1024), dim3(256), 0, stream, x, slots, hist);
    hipLaunchKernelGGL(kScanHist,    dim3(8),    dim3(256), 0, stream, hist, slots);
    hipLaunchKernelGGL(kCollect,     dim3(2048), dim3(256), 0, stream, x, slots, list);
    hipLaunchKernelGGL(kSelect,      dim3(8),    dim3(64),  0, stream, x, list, slots, P);
    hipLaunchKernelGGL(kBlur,        dim3(1536), dim3(256), 0, stream, x, out, P, slots, gk);
    hipLaunchKernelGGL(kFftRowFwdJC, dim3(1024), dim3(384), 0, stream, x, bufC, P, slots);
    hipLaunchKernelGGL(kFftColMid,   dim3(1024), dim3(256), 0, stream, bufC, lineS);
    hipLaunchKernelGGL(kNormParams,  dim3(1),    dim3(64),  0, stream, P, slots);
    hipLaunchKernelGGL(kCombineFFT,  dim3(1024), dim3(384), 0, stream, x, out, bufC, P, slots);
    hipLaunchKernelGGL(kFinalNorm,   dim3(6144), dim3(256), 0, stream, out, slots);
}

// Round 12
// 200.397 us; speedup vs baseline: 1.0593x; 1.0593x over previous
//
#include <hip/hip_runtime.h>
#include <math.h>

#define HW 262144          // 512*512
#define TOTAL 6291456      // 24*HW
#define PI_F 3.14159265358979323846f
#define NBIN 1024
#define PIDX(i) ((i) + ((i) >> 3))

// ---------------- ws layout (bytes) ----------------
// [0, 4096)           float  P[1024]         params
// [4096, 20480)       unsigned slots[4096]   pair-arrays + small state
// [20480, 53248)      unsigned hist[8*1024]
// [540672, 606208)    uint2  list[8*1024]
// [1048576, +32MB)    float2 bufC[16*HW]     packed FFT buffer (im = 2b: ch0+i*ch1, 2b+1: ch2)

// Params float offsets
#define PF_GATE 0
#define PF_WB 64
#define PF_GAMMA 88
#define PF_Y 96
#define PF_OMEGA 104
#define PF_ALPHA 112
#define PF_TC 120
#define PF_TSC 184
#define PF_RATE 192
#define PF_FG 200
#define PF_A 208
#define PF_WBM 256
#define PF_WBA 264
#define PF_GM 272
#define PF_GA 280
#define PF_SM 288
#define PF_SA 296
#define PF_FM 304
#define PF_FA 312
#define PF_CM 320
#define PF_CA 328
#define PF_TM 336
#define PF_TA 344
#define PF_LINE 360   // 8 ints
#define PF_TCS 368    // tc[k]*tsc, 8*8
#define PF_TPRE 432   // prefix sums, 8*8
#define PF_IA 496     // 1/a, 24

// quantity indices for min/max pair arrays: q*64 + s (min), q*64+32+s (max), s=0..31
#define QX(b,c) ((b)*3+(c))
#define QS 24
#define QJ 25
#define QC 26
#define QFIN 27
#define SL_LCOUNT 1792
#define SL_BINSTAR 1920
#define SL_RNEED 1928
#define SL_SUMA2 2048   // float[24][32]

struct GK { float w[13]; };

__device__ __forceinline__ void waveFence(){ __builtin_amdgcn_wave_barrier(); }

__device__ __forceinline__ unsigned fkey(float f){
    unsigned u = __float_as_uint(f);
    return (u & 0x80000000u) ? ~u : (u | 0x80000000u);
}
__device__ __forceinline__ float funkey(unsigned k){
    return (k & 0x80000000u) ? __uint_as_float(k & 0x7FFFFFFFu) : __uint_as_float(~k);
}

__device__ __forceinline__ void blockRedPair(unsigned kmn, unsigned kmx, int q,
                                             unsigned* slots, unsigned* lds8){
    #pragma unroll
    for (int o = 32; o > 0; o >>= 1){
        kmn = min(kmn, __shfl_down(kmn, o));
        kmx = max(kmx, __shfl_down(kmx, o));
    }
    int w = threadIdx.x >> 6;
    if ((threadIdx.x & 63) == 0){ lds8[w] = kmn; lds8[4+w] = kmx; }
    __syncthreads();
    if (threadIdx.x == 0){
        unsigned mn = min(min(lds8[0],lds8[1]), min(lds8[2],lds8[3]));
        unsigned mx = max(max(lds8[4],lds8[5]), max(lds8[6],lds8[7]));
        int s = blockIdx.x & 31;
        atomicMin(&slots[q*64 + s], mn);
        atomicMax(&slots[q*64 + 32 + s], mx);
    }
    __syncthreads();
}

__device__ __forceinline__ float toneF(float v, const float* tc, float tsc){
    float tn = 0.f;
    #pragma unroll
    for (int i = 0; i < 8; ++i){
        float d = v - 0.125f * (float)i;
        d = fminf(fmaxf(d, 0.f), 0.125f);
        tn += d * tc[i];
    }
    return tn * tsc;
}

// ---------------- complex helpers + radix-8 Stockham FFT (512 = 8^3) ----------------
__device__ __forceinline__ float2 cadd(float2 a, float2 b){ return make_float2(a.x+b.x, a.y+b.y); }
__device__ __forceinline__ float2 csub(float2 a, float2 b){ return make_float2(a.x-b.x, a.y-b.y); }
__device__ __forceinline__ float2 cmul(float2 a, float2 b){ return make_float2(a.x*b.x - a.y*b.y, a.x*b.y + a.y*b.x); }

template<int S>   // S=-1 fwd, S=+1 inv
__device__ __forceinline__ float2 rot90(float2 z){
    return (S < 0) ? make_float2(z.y, -z.x) : make_float2(-z.y, z.x);
}

template<int S>
__device__ __forceinline__ void fft4p(float2 a, float2 b, float2 c, float2 d,
                                      float2& X0, float2& X1, float2& X2, float2& X3){
    float2 t0 = cadd(a,c), t1 = csub(a,c), t2 = cadd(b,d), t3 = csub(b,d);
    float2 it3 = rot90<S>(t3);
    X0 = cadd(t0,t2); X2 = csub(t0,t2);
    X1 = cadd(t1,it3); X3 = csub(t1,it3);
}

template<int S>
__device__ __forceinline__ void bfly8(float2 v[8]){
    const float C = 0.70710678118654752f;
    float2 E0,E1,E2,E3,O0,O1,O2,O3;
    fft4p<S>(v[0],v[2],v[4],v[6], E0,E1,E2,E3);
    fft4p<S>(v[1],v[3],v[5],v[7], O0,O1,O2,O3);
    float2 w1 = make_float2(C, (S<0) ? -C : C);
    float2 w3 = make_float2(-C, (S<0) ? -C : C);
    float2 u1 = cmul(O1, w1);
    float2 u2 = rot90<S>(O2);
    float2 u3 = cmul(O3, w3);
    v[0]=cadd(E0,O0); v[4]=csub(E0,O0);
    v[1]=cadd(E1,u1); v[5]=csub(E1,u1);
    v[2]=cadd(E2,u2); v[6]=csub(E2,u2);
    v[3]=cadd(E3,u3); v[7]=csub(E3,u3);
}

__device__ __forceinline__ void twiddles(float2 v[8], float th){
    float sn, cs; __sincosf(th, &sn, &cs);
    float2 w1 = make_float2(cs, sn);
    float2 w = w1;
    v[1] = cmul(v[1], w1);
    #pragma unroll
    for (int r = 2; r < 8; ++r){ w = cmul(w, w1); v[r] = cmul(v[r], w); }
}

// Stockham FFT, natural in/out: v[r] = elem(lane + 64r). buf PRIVATE to this wave.
template<int S>
__device__ __forceinline__ void fft512reg(float2 v[8], float2* buf, int lane){
    bfly8<S>(v);
    #pragma unroll
    for (int q = 0; q < 8; ++q) buf[PIDX(8*lane + q)] = v[q];
    waveFence();
    #pragma unroll
    for (int r = 0; r < 8; ++r) v[r] = buf[PIDX(lane + 64*r)];
    waveFence();
    twiddles(v, (float)S * 6.2831853072f * (float)(lane & 7) * (1.0f/64.0f));
    bfly8<S>(v);
    {
        int basei = ((lane >> 3) << 6) + (lane & 7);
        #pragma unroll
        for (int q = 0; q < 8; ++q) buf[PIDX(basei + 8*q)] = v[q];
    }
    waveFence();
    #pragma unroll
    for (int r = 0; r < 8; ++r) v[r] = buf[PIDX(lane + 64*r)];
    waveFence();
    twiddles(v, (float)S * 6.2831853072f * (float)lane * (1.0f/512.0f));
    bfly8<S>(v);
}

// ---------------- setup ----------------
__global__ __launch_bounds__(256) void kSetup(
    const float* __restrict__ lat,
    const float* gw, const float* gb, const float* wbw, const float* wbb,
    const float* gaw, const float* gab, const float* shw, const float* shb,
    const float* dfw, const float* dfb, const float* ctw, const float* ctb,
    const float* tow, const float* tob, const float* ffw, const float* ffb,
    float* P, unsigned* slots, unsigned* hist)
{
    if (blockIdx.x != 0){
        int i = (blockIdx.x - 1) * 256 + threadIdx.x;
        if (i < 4096) slots[i] = (i < 1792 && (i & 63) < 32) ? 0xFFFFFFFFu : 0u;
        if (i < 8192) hist[i] = 0u;
        return;
    }
    int t = threadIdx.x;
    if (t < 192){
        int b = t / 24, o = t % 24;
        const float* L = lat + b * 256;
        const float* W; float bias; int nc, col;
        if (o < 8)      { W=gw;  bias=gb[o];     nc=8; col=o;    }
        else if (o < 11){ W=wbw; bias=wbb[o-8];  nc=3; col=o-8;  }
        else if (o==11) { W=gaw; bias=gab[0];    nc=1; col=0;    }
        else if (o==12) { W=shw; bias=shb[0];    nc=1; col=0;    }
        else if (o==13) { W=dfw; bias=dfb[0];    nc=1; col=0;    }
        else if (o==14) { W=ctw; bias=ctb[0];    nc=1; col=0;    }
        else if (o<23)  { W=tow; bias=tob[o-15]; nc=8; col=o-15; }
        else            { W=ffw; bias=ffb[0];    nc=1; col=0;    }
        float acc = bias;
        for (int d = 0; d < 256; ++d) acc += L[d] * W[d*nc + col];
        float t01 = tanhf(acc) * 0.5f + 0.5f;
        if (o < 8){ float v = t01*0.99f + 0.01f; P[PF_GATE + b*8 + o] = v; if (o==7) P[PF_FG + b] = v; }
        else if (o < 11){ P[PF_WB + b*3 + (o-8)] = expf(t01 - 0.5f); }
        else if (o==11){ float lg = logf(2.5f); P[PF_GAMMA + b] = expf(t01*(2.f*lg) - lg); }
        else if (o==12){ P[PF_Y + b] = t01*0.9f + 0.1f; }
        else if (o==13){ P[PF_OMEGA + b] = t01*0.9f + 0.1f; }
        else if (o==14){ P[PF_ALPHA + b] = tanhf(acc); }
        else if (o<23){ P[PF_TC + b*8 + (o-15)] = t01*1.5f + 0.5f; }
        else { P[PF_RATE + b] = t01*0.7f + 0.1f; }
    }
    __syncthreads();
    if (t < 8){
        int b = t;
        float w0=P[PF_WB+b*3], w1=P[PF_WB+b*3+1], w2=P[PF_WB+b*3+2];
        float cs = 1.0f / (1e-5f + 0.27f*w0 + 0.67f*w1 + 0.06f*w2);
        P[PF_WB+b*3] = cs*w0; P[PF_WB+b*3+1] = cs*w1; P[PF_WB+b*3+2] = cs*w2;
        float ts = 0.f;
        for (int i = 0; i < 8; ++i) ts += P[PF_TC + b*8 + i];
        float tsc = 8.0f / (ts + 1e-30f);
        P[PF_TSC + b] = tsc;
        float acc = 0.f;
        for (int k = 0; k < 8; ++k){
            float tck = P[PF_TC + b*8 + k] * tsc;
            P[PF_TCS + b*8 + k] = tck;
            P[PF_TPRE + b*8 + k] = acc;
            acc += tck * 0.125f;
        }
        int bs = (b + 4) & 7; // fftshift batch roll
        ((int*)(P + PF_LINE))[b] = (int)floorf(sqrtf(262144.0f * P[PF_RATE + bs]) * 0.5f);
    }
}

// ---------------- x min/max per (b,c) + dark histogram ----------------
__global__ __launch_bounds__(256) void kMinmaxHist(const float* __restrict__ x, unsigned* slots, unsigned* hist){
    __shared__ unsigned h[NBIN];
    __shared__ unsigned lds8[8];
    int b = blockIdx.x >> 7;
    int blk = blockIdx.x & 127;
    for (int i = threadIdx.x; i < NBIN; i += 256) h[i] = 0u;
    __syncthreads();
    size_t xb = (size_t)b*3*HW;
    int p0 = (((blk<<1)    )*256 + threadIdx.x) << 2;
    int p1 = (((blk<<1) + 1)*256 + threadIdx.x) << 2;
    float4 u0 = *(const float4*)(x + xb + p0);
    float4 u1 = *(const float4*)(x + xb + HW + p0);
    float4 u2 = *(const float4*)(x + xb + 2*HW + p0);
    float4 w0 = *(const float4*)(x + xb + p1);
    float4 w1 = *(const float4*)(x + xb + HW + p1);
    float4 w2 = *(const float4*)(x + xb + 2*HW + p1);
    float a0[8] = {u0.x,u0.y,u0.z,u0.w, w0.x,w0.y,w0.z,w0.w};
    float a1[8] = {u1.x,u1.y,u1.z,u1.w, w1.x,w1.y,w1.z,w1.w};
    float a2[8] = {u2.x,u2.y,u2.z,u2.w, w2.x,w2.y,w2.z,w2.w};
    float mn0=1e30f,mx0=-1e30f,mn1=1e30f,mx1=-1e30f,mn2=1e30f,mx2=-1e30f;
    #pragma unroll
    for (int e = 0; e < 8; ++e){
        float dark = fminf(a0[e], fminf(a1[e], a2[e]));
        atomicAdd(&h[min(NBIN-1, (int)(dark * (float)NBIN))], 1u);
        mn0 = fminf(mn0, a0[e]); mx0 = fmaxf(mx0, a0[e]);
        mn1 = fminf(mn1, a1[e]); mx1 = fmaxf(mx1, a1[e]);
        mn2 = fminf(mn2, a2[e]); mx2 = fmaxf(mx2, a2[e]);
    }
    __syncthreads();
    for (int i = threadIdx.x; i < NBIN; i += 256){
        unsigned c = h[i];
        if (c) atomicAdd(&hist[b*NBIN + i], c);
    }
    blockRedPair(fkey(mn0), fkey(mx0), QX(b,0), slots, lds8);
    blockRedPair(fkey(mn1), fkey(mx1), QX(b,1), slots, lds8);
    blockRedPair(fkey(mn2), fkey(mx2), QX(b,2), slots, lds8);
}

// ---------------- descending scan of histogram -> threshold bin ----------------
__global__ __launch_bounds__(256) void kScanHist(const unsigned* __restrict__ hist, unsigned* slots){
    int b = blockIdx.x, t = threadIdx.x;
    __shared__ unsigned wtot[4];
    __shared__ int doneS;
    if (t == 0) doneS = 0;
    __syncthreads();
    unsigned total = 0;
    for (int c0 = 0; c0 < NBIN; c0 += 256){
        int binIdx = NBIN-1 - (c0 + t);
        unsigned cnt = hist[b*NBIN + binIdx];
        unsigned v = cnt;
        #pragma unroll
        for (int off = 1; off < 64; off <<= 1){
            unsigned u = __shfl_up(v, off);
            if ((t & 63) >= off) v += u;
        }
        if ((t & 63) == 63) wtot[t >> 6] = v;
        __syncthreads();
        unsigned wofs = 0;
        for (int w = 0; w < (t >> 6); ++w) wofs += wtot[w];
        unsigned incl = total + wofs + v;
        unsigned excl = incl - cnt;
        if (incl >= 261u && excl < 261u){
            slots[SL_BINSTAR + b] = (unsigned)binIdx;
            slots[SL_RNEED + b]   = 261u - excl;
            doneS = 1;
        }
        __syncthreads();
        if (doneS) break;
        total += wtot[0] + wtot[1] + wtot[2] + wtot[3];
        __syncthreads();
    }
}

// ---------------- collect: block-reduced above-threshold sums + boundary list ----------------
__global__ __launch_bounds__(256) void kCollect(const float* __restrict__ x, unsigned* slots, uint2* list){
    __shared__ float wsum[3][4];
    int b = blockIdx.x >> 8;
    int tile = blockIdx.x & 255;
    size_t xb = (size_t)b*3*HW;
    int p = (tile*256 + threadIdx.x) << 2;
    float4 v0 = *(const float4*)(x + xb + p);
    float4 v1 = *(const float4*)(x + xb + HW + p);
    float4 v2 = *(const float4*)(x + xb + 2*HW + p);
    int bs = (int)slots[SL_BINSTAR + b];
    float a0[4] = {v0.x,v0.y,v0.z,v0.w};
    float a1[4] = {v1.x,v1.y,v1.z,v1.w};
    float a2[4] = {v2.x,v2.y,v2.z,v2.w};
    float s0 = 0.f, s1 = 0.f, s2 = 0.f;
    #pragma unroll
    for (int e = 0; e < 4; ++e){
        float dark = fminf(a0[e], fminf(a1[e], a2[e]));
        int bin = min(NBIN-1, (int)(dark * (float)NBIN));
        if (bin > bs){ s0 += a0[e]; s1 += a1[e]; s2 += a2[e]; }
        else if (bin == bs){
            unsigned n = atomicAdd(&slots[SL_LCOUNT + b], 1u);
            if (n < 1024u) list[(b << 10) + n] = make_uint2(__float_as_uint(dark), (unsigned)(p + e));
        }
    }
    #pragma unroll
    for (int o = 32; o > 0; o >>= 1){
        s0 += __shfl_down(s0, o); s1 += __shfl_down(s1, o); s2 += __shfl_down(s2, o);
    }
    int w = threadIdx.x >> 6;
    if ((threadIdx.x & 63) == 0){ wsum[0][w] = s0; wsum[1][w] = s1; wsum[2][w] = s2; }
    __syncthreads();
    if (threadIdx.x == 0){
        float t0 = wsum[0][0]+wsum[0][1]+wsum[0][2]+wsum[0][3];
        float t1 = wsum[1][0]+wsum[1][1]+wsum[1][2]+wsum[1][3];
        float t2 = wsum[2][0]+wsum[2][1]+wsum[2][2]+wsum[2][3];
        float* F = (float*)(slots + SL_SUMA2);
        int sl = blockIdx.x & 31;
        atomicAdd(&F[(b*3+0)*32 + sl], t0);
        atomicAdd(&F[(b*3+1)*32 + sl], t1);
        atomicAdd(&F[(b*3+2)*32 + sl], t2);
    }
}

// ---------------- finish atmospheric light: wave-parallel top-r selection ----------------
__global__ void kSelect(const float* __restrict__ x, uint2* list, unsigned* slots, float* P){
    __shared__ unsigned pid[262];
    __shared__ char taken[1024];
    int b = blockIdx.x, t = threadIdx.x;  // 64 threads
    int n = (int)min(slots[SL_LCOUNT + b], 1024u);
    int r = (int)slots[SL_RNEED + b];
    if (r > n) r = n;
    const uint2* L = &list[b << 10];
    for (int i = t; i < n; i += 64) taken[i] = 0;
    __syncthreads();
    for (int it = 0; it < r; ++it){
        unsigned long long bk = 0ull; int bp = -1;
        for (int i = t; i < n; i += 64){
            if (taken[i]) continue;
            uint2 e = L[i];
            unsigned long long key = ((unsigned long long)e.x << 32) | e.y;
            if (key > bk){ bk = key; bp = i; }
        }
        #pragma unroll
        for (int o = 32; o > 0; o >>= 1){
            unsigned long long ok = __shfl_down(bk, o);
            int op = __shfl_down(bp, o);
            if (ok > bk){ bk = ok; bp = op; }
        }
        bp = __shfl(bp, 0);
        if (t == 0){ pid[it] = L[bp].y; taken[bp] = 1; }
        __syncthreads();
    }
    float s0 = 0.f, s1 = 0.f, s2 = 0.f;
    size_t xb = (size_t)b*3*HW;
    for (int i = t; i < r; i += 64){
        unsigned id = pid[i];
        s0 += x[xb + id]; s1 += x[xb + HW + id]; s2 += x[xb + 2*HW + id];
    }
    #pragma unroll
    for (int o = 32; o > 0; o >>= 1){
        s0 += __shfl_down(s0, o); s1 += __shfl_down(s1, o); s2 += __shfl_down(s2, o);
    }
    if (t == 0){
        const float* F = (const float*)(slots + SL_SUMA2);
        float f0 = 0.f, f1 = 0.f, f2 = 0.f;
        for (int k = 0; k < 32; ++k){
            f0 += F[(b*3+0)*32 + k];
            f1 += F[(b*3+1)*32 + k];
            f2 += F[(b*3+2)*32 + k];
        }
        float A0 = (s0 + f0) / 262.0f, A1 = (s1 + f1) / 262.0f, A2 = (s2 + f2) / 262.0f;
        P[PF_A + b*3+0] = A0; P[PF_A + b*3+1] = A1; P[PF_A + b*3+2] = A2;
        P[PF_IA + b*3+0] = 1.0f/A0; P[PF_IA + b*3+1] = 1.0f/A1; P[PF_IA + b*3+2] = 1.0f/A2;
    }
}

// ---------------- fused gaussian blur; stores SHARPENED value s = x + y*(x-blur) ----------------
__global__ __launch_bounds__(256) void kBlur(const float* __restrict__ x, float* __restrict__ sharpOut,
                                             const float* __restrict__ P, unsigned* slots, GK gk){
    __shared__ float tile[76][80];
    __shared__ float hbuf[76][68];
    __shared__ unsigned lds8[8];
    int img = blockIdx.x >> 6;
    int tid = blockIdx.x & 63;
    int tr0 = (tid >> 3) << 6;
    int tc0 = (tid & 7) << 6;
    size_t ib = (size_t)img * HW;
    int t = threadIdx.x;
    for (int l = t; l < 76*76; l += 256){
        int r = l / 76, c = l - r*76;
        int gr = tr0 + r - 6; gr = (gr < 0) ? -gr : ((gr > 511) ? 1022 - gr : gr);
        int gc = tc0 + c - 6; gc = (gc < 0) ? -gc : ((gc > 511) ? 1022 - gc : gc);
        tile[r][c] = x[ib + ((size_t)gr << 9) + gc];
    }
    __syncthreads();
    for (int l = t; l < 76*64; l += 256){
        int r = l >> 6, c = l & 63;
        float acc = 0.f;
        #pragma unroll
        for (int k = 0; k < 13; ++k) acc += gk.w[k] * tile[r][c + k];
        hbuf[r][c] = acc;
    }
    __syncthreads();
    float yb = P[PF_Y + img/3];
    unsigned kmn = 0xFFFFFFFFu, kmx = 0u;
    for (int l = t; l < 64*64; l += 256){
        int r = l >> 6, c = l & 63;
        float acc = 0.f;
        #pragma unroll
        for (int k = 0; k < 13; ++k) acc += gk.w[k] * hbuf[r + k][c];
        float xv = tile[r + 6][c + 6];
        float s = xv + yb * (xv - acc);
        sharpOut[ib + ((size_t)(tr0 + r) << 9) + tc0 + c] = s;
        unsigned key = fkey(s);
        kmn = min(kmn, key); kmx = max(kmx, key);
    }
    blockRedPair(kmn, kmx, QS, slots, lds8);
}

// ---------------- fused: fwd row FFT (ch0+i*ch1 packed, ch2) on row pair + JC min/max ----------------
// LDS: xs (12.3KB) time-shared with Stockham buf (18.6KB) via alias
__global__ __launch_bounds__(256) void kFftRowFwdJC(const float* __restrict__ x, float2* __restrict__ bc,
                                                    const float* __restrict__ P, unsigned* slots){
    __shared__ float2 buf4[4][580];
    __shared__ unsigned lds8[8];
    float (*xs)[3][512] = reinterpret_cast<float(*)[3][512]>(&buf4[0][0]);
    int b = blockIdx.x >> 8;
    int rp = blockIdx.x & 255;
    int t = threadIdx.x;
    #pragma unroll
    for (int k = 0; k < 3; ++k){
        int l = t + (k << 8);          // 0..767
        int seg = l >> 7;              // 0..5
        int idx = (l & 127) << 2;
        int ch = seg >> 1, rr = seg & 1;
        float4 z = *(const float4*)(x + (size_t)(3*b + ch)*HW + ((size_t)(2*rp + rr) << 9) + idx);
        *(float4*)&xs[rr][ch][idx] = z;
    }
    __syncthreads();
    // JC min/max over the 2 rows
    {
        float ia0 = P[PF_IA+b*3], ia1 = P[PF_IA+b*3+1], ia2 = P[PF_IA+b*3+2];
        float a0 = P[PF_A+b*3],  a1 = P[PF_A+b*3+1],  a2 = P[PF_A+b*3+2];
        float om = P[PF_OMEGA+b], al = P[PF_ALPHA+b];
        int rr = t >> 7, c4 = (t & 127) << 2;
        float4 xv0 = *(float4*)&xs[rr][0][c4];
        float4 xv1 = *(float4*)&xs[rr][1][c4];
        float4 xv2 = *(float4*)&xs[rr][2][c4];
        float A0[4]={xv0.x,xv0.y,xv0.z,xv0.w}, A1[4]={xv1.x,xv1.y,xv1.z,xv1.w}, A2[4]={xv2.x,xv2.y,xv2.z,xv2.w};
        float jmn = 1e30f, jmx = -1e30f, cmn = 1e30f, cmx = -1e30f;
        #pragma unroll
        for (int e = 0; e < 4; ++e){
            float x0 = A0[e], x1 = A1[e], x2 = A2[e];
            float dr = fminf(x0*ia0, fminf(x1*ia1, x2*ia2));
            float T = fmaxf(1.0f - om*dr, 0.01f);
            float rT = 1.0f / T;
            float j0 = (x0-a0)*rT + a0, j1 = (x1-a1)*rT + a1, j2 = (x2-a2)*rT + a2;
            float lum = fminf(fmaxf(0.27f*x0 + 0.67f*x1 + 0.06f*x2, 0.f), 1.f);
            float clum = -__cosf(PI_F*lum)*0.5f + 0.5f;
            float alx = (1.f - al) + al * (clum / (lum + 1e-6f));
            float c0 = x0*alx, c1 = x1*alx, c2 = x2*alx;
            jmn = fminf(jmn, fminf(j0, fminf(j1, j2))); jmx = fmaxf(jmx, fmaxf(j0, fmaxf(j1, j2)));
            cmn = fminf(cmn, fminf(c0, fminf(c1, c2))); cmx = fmaxf(cmx, fmaxf(c0, fmaxf(c1, c2)));
        }
        blockRedPair(fkey(jmn), fkey(jmx), QJ, slots, lds8);
        blockRedPair(fkey(cmn), fkey(cmx), QC, slots, lds8);
    }
    // 4 FFT units: u = {row, pack}. Load v from xs, then hand LDS over to Stockham buf.
    int u = t >> 6, lane = t & 63;
    int frr = u >> 1, pk = u & 1;
    float2 v[8];
    #pragma unroll
    for (int r = 0; r < 8; ++r){
        int i = lane + 64*r;
        if (pk == 0) v[r] = make_float2(xs[frr][0][i] * (1.0f/512.0f), xs[frr][1][i] * (1.0f/512.0f));
        else         v[r] = make_float2(xs[frr][2][i] * (1.0f/512.0f), 0.f);
    }
    __syncthreads();   // all xs reads done before buf overwrites the region (cross-wave alias)
    fft512reg<-1>(v, buf4[u], lane);
    size_t ob = (size_t)(2*b + pk)*HW + ((size_t)(2*rp + frr) << 9);
    #pragma unroll
    for (int q = 0; q < 8; ++q) bc[ob + lane + 64*q] = v[q];
}

// ---------------- FFT column pass: 8-col coalesced tile, fwd + mask + inv (16 packed images) ----------------
__global__ __launch_bounds__(256) void kFftColMid(float2* __restrict__ bc, const int* __restrict__ lineS){
    int img  = blockIdx.x >> 6;
    int tile = blockIdx.x & 63;
    int c0 = tile << 3;
    int line = lineS[img >> 1];
    if (c0 >= line && c0 + 8 <= 512 - line) return;  // tile fully unmasked: identity
    __shared__ float2 cb[8][580];
    int t = threadIdx.x;
    size_t ibase = (size_t)img*HW + c0;
    for (int k = 0; k < 16; ++k){
        int idx = (k << 8) + t;
        int row = idx >> 3, col = idx & 7;
        float2 z = bc[ibase + ((size_t)row << 9) + col];
        cb[col][PIDX(row)] = make_float2(z.x * (1.0f/512.0f), z.y * (1.0f/512.0f));
    }
    __syncthreads();
    int lane = t & 63, u = t >> 6;
    #pragma unroll
    for (int h = 0; h < 2; ++h){
        int col = (h << 2) + u;          // disjoint col sets per h -> no cross-wave hazard
        int cc = c0 + col;
        bool colM = (cc < line) || (cc >= 512 - line);
        float2 v[8];
        #pragma unroll
        for (int r = 0; r < 8; ++r) v[r] = cb[col][PIDX(lane + 64*r)];
        waveFence();
        fft512reg<-1>(v, cb[col], lane);
        if (colM){
            #pragma unroll
            for (int q = 0; q < 8; ++q){
                int f = lane + (q << 6);
                if (f < line || f >= 512 - line) v[q] = make_float2(0.f, 0.f);
            }
        }
        waveFence();
        fft512reg<+1>(v, cb[col], lane);
        #pragma unroll
        for (int q = 0; q < 8; ++q) cb[col][PIDX(lane + 64*q)] = v[q];
        waveFence();
    }
    __syncthreads();
    for (int k = 0; k < 16; ++k){
        int idx = (k << 8) + t;
        int row = idx >> 3, col = idx & 7;
        int cc = c0 + col;
        if (cc < line || cc >= 512 - line)
            bc[ibase + ((size_t)row << 9) + col] = cb[col][PIDX(row)];
    }
}

// ---------------- fused: inverse row FFT (packed) on row pair + combine ----------------
// LDS: Stockham buf (18.6KB) time-shared with fbuf (12.3KB) via alias
__global__ __launch_bounds__(256) void kCombineFFT(const float* __restrict__ x, float* __restrict__ outb,
                                                   const float2* __restrict__ bc, const float* __restrict__ P,
                                                   unsigned* slots){
    __shared__ float2 buf4[4][580];
    __shared__ float stc[8], spre[8];
    __shared__ unsigned lds8[8];
    float (*fbuf)[3][512] = reinterpret_cast<float(*)[3][512]>(&buf4[0][0]);
    int b = blockIdx.x >> 8;
    int rp = blockIdx.x & 255;
    int t = threadIdx.x;
    if (t < 8){ stc[t] = P[PF_TCS + b*8 + t]; spre[t] = P[PF_TPRE + b*8 + t]; }
    int u = t >> 6, lane = t & 63;
    int frr = u >> 1, pk = u & 1;
    float2 v[8];
    size_t ib = (size_t)(2*b + pk)*HW + ((size_t)(2*rp + frr) << 9);
    #pragma unroll
    for (int r = 0; r < 8; ++r) v[r] = bc[ib + lane + 64*r];
    fft512reg<+1>(v, buf4[u], lane);
    __syncthreads();   // all buf reads done before fbuf overwrites the region (cross-wave alias)
    if (pk == 0){
        #pragma unroll
        for (int q = 0; q < 8; ++q){
            int i = lane + 64*q;
            fbuf[frr][0][i] = fabsf(v[q].x);
            fbuf[frr][1][i] = fabsf(v[q].y);
        }
    } else {
        #pragma unroll
        for (int q = 0; q < 8; ++q) fbuf[frr][2][lane + 64*q] = fabsf(v[q].x);
    }
    __syncthreads();

    float g  = P[PF_FG + b];
    float wb0=P[PF_WB+b*3], wb1=P[PF_WB+b*3+1], wb2=P[PF_WB+b*3+2];
    float gam=P[PF_GAMMA+b], om=P[PF_OMEGA+b], al=P[PF_ALPHA+b];
    float a0=P[PF_A+b*3], a1=P[PF_A+b*3+1], a2=P[PF_A+b*3+2];
    float ia0=P[PF_IA+b*3], ia1=P[PF_IA+b*3+1], ia2=P[PF_IA+b*3+2];
    float g2=P[PF_GATE+b*8+2];
    float wbm=P[PF_WBM+b], wba=P[PF_WBA+b], gm=P[PF_GM+b], ga=P[PF_GA+b];
    float sm=P[PF_SM+b], sa=P[PF_SA+b], fm=P[PF_FM+b], fa=P[PF_FA+b];
    float cm=P[PF_CM+b], ca=P[PF_CA+b], tm=P[PF_TM+b], ta=P[PF_TA+b];
    float kadd = wba + ga + sa + fa + ca + ta;
    float cw0 = wb0*wbm + g2, cw1 = wb1*wbm + g2, cw2 = wb2*wbm + g2;

    int rr = t >> 7, c4 = (t & 127) << 2;
    size_t p0 = (size_t)(3*b)*HW + ((size_t)(2*rp + rr) << 9) + c4;
    float4 xv0 = *(const float4*)(x + p0);
    float4 xv1 = *(const float4*)(x + p0 + HW);
    float4 xv2 = *(const float4*)(x + p0 + 2*HW);
    float4 sv0 = *(const float4*)(outb + p0);
    float4 sv1 = *(const float4*)(outb + p0 + HW);
    float4 sv2 = *(const float4*)(outb + p0 + 2*HW);
    float4 fv0 = *(float4*)&fbuf[rr][0][c4];
    float4 fv1 = *(float4*)&fbuf[rr][1][c4];
    float4 fv2 = *(float4*)&fbuf[rr][2][c4];
    float X0[4]={xv0.x,xv0.y,xv0.z,xv0.w}, X1[4]={xv1.x,xv1.y,xv1.z,xv1.w}, X2[4]={xv2.x,xv2.y,xv2.z,xv2.w};
    float S0[4]={sv0.x,sv0.y,sv0.z,sv0.w}, S1[4]={sv1.x,sv1.y,sv1.z,sv1.w}, S2[4]={sv2.x,sv2.y,sv2.z,sv2.w};
    float F0[4]={fv0.x,fv0.y,fv0.z,fv0.w}, F1[4]={fv1.x,fv1.y,fv1.z,fv1.w}, F2[4]={fv2.x,fv2.y,fv2.z,fv2.w};
    float O0[4], O1[4], O2[4];
    float mn = 1e30f, mx = -1e30f;
    #pragma unroll
    for (int e = 0; e < 4; ++e){
        float x0 = X0[e], x1 = X1[e], x2 = X2[e];
        float dr = fminf(x0*ia0, fminf(x1*ia1, x2*ia2));
        float T = fmaxf(1.0f - om*dr, 0.01f);
        float rT = 1.0f / T;
        float lum = fminf(fmaxf(0.27f*x0 + 0.67f*x1 + 0.06f*x2, 0.f), 1.f);
        float clum = -__cosf(PI_F*lum)*0.5f + 0.5f;
        float alx = (1.f - al) + al * (clum / (lum + 1e-6f));
        // ch0
        {
            float j = (x0 - a0)*rT + a0;
            int k = min(7, (int)(x0 * 8.0f));
            float tn = spre[k] + (x0 - 0.125f*(float)k) * stc[k];
            float gp = __powf(fmaxf(x0, 1e-4f), gam);
            float sum = x0*cw0 + gp*gm + S0[e]*sm + j*fm + (x0*alx)*cm + tn*tm + kadd + F0[e]*g;
            O0[e] = sum; mn = fminf(mn, sum); mx = fmaxf(mx, sum);
        }
        // ch1
        {
            float j = (x1 - a1)*rT + a1;
            int k = min(7, (int)(x1 * 8.0f));
            float tn = spre[k] + (x1 - 0.125f*(float)k) * stc[k];
            float gp = __powf(fmaxf(x1, 1e-4f), gam);
            float sum = x1*cw1 + gp*gm + S1[e]*sm + j*fm + (x1*alx)*cm + tn*tm + kadd + F1[e]*g;
            O1[e] = sum; mn = fminf(mn, sum); mx = fmaxf(mx, sum);
        }
        // ch2
        {
            float j = (x2 - a2)*rT + a2;
            int k = min(7, (int)(x2 * 8.0f));
            float tn = spre[k] + (x2 - 0.125f*(float)k) * stc[k];
            float gp = __powf(fmaxf(x2, 1e-4f), gam);
            float sum = x2*cw2 + gp*gm + S2[e]*sm + j*fm + (x2*alx)*cm + tn*tm + kadd + F2[e]*g;
            O2[e] = sum; mn = fminf(mn, sum); mx = fmaxf(mx, sum);
        }
    }
    *(float4*)(outb + p0)        = make_float4(O0[0],O0[1],O0[2],O0[3]);
    *(float4*)(outb + p0 + HW)   = make_float4(O1[0],O1[1],O1[2],O1[3]);
    *(float4*)(outb + p0 + 2*HW) = make_float4(O2[0],O2[1],O2[2],O2[3]);
    blockRedPair(fkey(mn), fkey(mx), QFIN, slots, lds8);
}

// ---------------- normalization params ----------------
__global__ void kNormParams(float* P, const unsigned* __restrict__ slots){
    __shared__ float mnv[28], mxv[28];
    int t = threadIdx.x;
    if (t < 28){
        unsigned kmn = 0xFFFFFFFFu, kmx = 0u;
        for (int s = 0; s < 32; ++s){
            kmn = min(kmn, slots[t*64 + s]);
            kmx = max(kmx, slots[t*64 + 32 + s]);
        }
        mnv[t] = funkey(kmn); mxv[t] = funkey(kmx);
    }
    __syncthreads();
    if (t == 0){
        float wmin=1e30f, wmax=-1e30f, gmin=1e30f, gmax=-1e30f, tmin=1e30f, tmax=-1e30f;
        for (int b = 0; b < 8; ++b){
            float gam = P[PF_GAMMA+b];
            float tsc = P[PF_TSC+b];
            const float* tc = &P[PF_TC + b*8];
            float xbmin = 1e30f, xbmax = -1e30f;
            for (int c = 0; c < 3; ++c){
                int i = b*3 + c;
                float w = P[PF_WB + i];
                wmin = fminf(wmin, w * mnv[i]); wmax = fmaxf(wmax, w * mxv[i]);
                gmin = fminf(gmin, __powf(fmaxf(mnv[i], 1e-4f), gam));
                gmax = fmaxf(gmax, __powf(fmaxf(mxv[i], 1e-4f), gam));
                xbmin = fminf(xbmin, mnv[i]); xbmax = fmaxf(xbmax, mxv[i]);
            }
            tmin = fminf(tmin, toneF(xbmin, tc, tsc));
            tmax = fmaxf(tmax, toneF(xbmax, tc, tsc));
        }
        float smin = mnv[QS], smax = mxv[QS];
        float jmin = mnv[QJ], jmax = mxv[QJ];
        float cmin = mnv[QC], cmax = mxv[QC];
        for (int b = 0; b < 8; ++b){
            const float* G = &P[PF_GATE + b*8];
            float m;
            m = G[0]/(wmax-wmin); P[PF_WBM+b]=m; P[PF_WBA+b]=-wmin*m;
            m = G[1]/(gmax-gmin); P[PF_GM +b]=m; P[PF_GA +b]=-gmin*m;
            m = G[3]/(smax-smin); P[PF_SM +b]=m; P[PF_SA +b]=-smin*m;
            m = G[4]/(jmax-jmin); P[PF_FM +b]=m; P[PF_FA +b]=-jmin*m;
            m = G[5]/(cmax-cmin); P[PF_CM +b]=m; P[PF_CA +b]=-cmin*m;
            m = G[6]/(tmax-tmin); P[PF_TM +b]=m; P[PF_TA +b]=-tmin*m;
        }
    }
}

__global__ __launch_bounds__(256) void kFinalNorm(float* __restrict__ out, const unsigned* __restrict__ slots){
    unsigned kmn = 0xFFFFFFFFu, kmx = 0u;
    for (int s = 0; s < 32; ++s){
        kmn = min(kmn, slots[QFIN*64 + s]);
        kmx = max(kmx, slots[QFIN*64 + 32 + s]);
    }
    float mn = funkey(kmn), mx = funkey(kmx);
    float inv = 1.0f / (mx - mn);
    size_t i = ((size_t)blockIdx.x*256 + threadIdx.x) << 2;
    float4 v = *(const float4*)(out + i);
    v.x = (v.x - mn) * inv; v.y = (v.y - mn) * inv;
    v.z = (v.z - mn) * inv; v.w = (v.w - mn) * inv;
    *(float4*)(out + i) = v;
}

extern "C" void kernel_launch(void* const* d_in, const int* in_sizes, int n_in,
                              void* d_out, int out_size, void* d_ws, size_t ws_size,
                              hipStream_t stream){
    const float* x   = (const float*)d_in[0];
    const float* lat = (const float*)d_in[1];
    const float* gw  = (const float*)d_in[2];  const float* gb  = (const float*)d_in[3];
    const float* wbw = (const float*)d_in[4];  const float* wbb = (const float*)d_in[5];
    const float* gaw = (const float*)d_in[6];  const float* gab = (const float*)d_in[7];
    const float* shw = (const float*)d_in[8];  const float* shb = (const float*)d_in[9];
    const float* dfw = (const float*)d_in[10]; const float* dfb = (const float*)d_in[11];
    const float* ctw = (const float*)d_in[12]; const float* ctb = (const float*)d_in[13];
    const float* tow = (const float*)d_in[14]; const float* tob = (const float*)d_in[15];
    const float* ffw = (const float*)d_in[16]; const float* ffb = (const float*)d_in[17];
    float* out = (float*)d_out;
    char* ws = (char*)d_ws;

    float*    P     = (float*)ws;
    unsigned* slots = (unsigned*)(ws + 4096);
    unsigned* hist  = (unsigned*)(ws + 20480);
    uint2*    list  = (uint2*)(ws + 540672);
    float2*   bufC  = (float2*)(ws + 1048576);
    const int* lineS = (const int*)(P + PF_LINE);

    GK gk;
    {
        float s = 0.f;
        for (int i = 0; i < 13; ++i){ float t = (float)i - 6.f; gk.w[i] = expf(-(t*t)/8.0f); s += gk.w[i]; }
        for (int i = 0; i < 13; ++i) gk.w[i] /= s;
    }

    hipLaunchKernelGGL(kSetup,       dim3(41),   dim3(256), 0, stream, lat, gw,gb,wbw,wbb,gaw,gab,shw,shb,dfw,dfb,ctw,ctb,tow,tob,ffw,ffb, P, slots, hist);
    hipLaunchKernelGGL(kMinmaxHist,  dim3(1024), dim3(256), 0, stream, x, slots, hist);
    hipLaunchKernelGGL(kScanHist,    dim3(8),    dim3(256), 0, stream, hist, slots);
    hipLaunchKernelGGL(kCollect,     dim3(2048), dim3(256), 0, stream, x, slots, list);
    hipLaunchKernelGGL(kSelect,      dim3(8),    dim3(64),  0, stream, x, list, slots, P);
    hipLaunchKernelGGL(kBlur,        dim3(1536), dim3(256), 0, stream, x, out, P, slots, gk);
    hipLaunchKernelGGL(kFftRowFwdJC, dim3(2048), dim3(256), 0, stream, x, bufC, P, slots);
    hipLaunchKernelGGL(kFftColMid,   dim3(1024), dim3(256), 0, stream, bufC, lineS);
    hipLaunchKernelGGL(kNormParams,  dim3(1),    dim3(64),  0, stream, P, slots);
    hipLaunchKernelGGL(kCombineFFT,  dim3(2048), dim3(256), 0, stream, x, out, bufC, P, slots);
    hipLaunchKernelGGL(kFinalNorm,   dim3(6144), dim3(256), 0, stream, out, slots);
}

// Round 13
// 198.854 us; speedup vs baseline: 1.0675x; 1.0078x over previous
//
#include <hip/hip_runtime.h>
#include <math.h>

#define HW 262144          // 512*512
#define TOTAL 6291456      // 24*HW
#define PI_F 3.14159265358979323846f
#define NBIN 1024
#define PIDX(i) ((i) + ((i) >> 3))

// ---------------- ws layout (bytes) ----------------
// [0, 4096)           float  P[1024]         params
// [4096, 20480)       unsigned slots[4096]   pair-arrays + small state
// [20480, 53248)      unsigned hist[8*1024]
// [540672, 606208)    uint2  list[8*1024]
// [1048576, +32MB)    float2 bufC[16*HW]     packed FFT buffer (im = 2b: ch0+i*ch1, 2b+1: ch2)

// Params float offsets
#define PF_GATE 0
#define PF_WB 64
#define PF_GAMMA 88
#define PF_Y 96
#define PF_OMEGA 104
#define PF_ALPHA 112
#define PF_TC 120
#define PF_TSC 184
#define PF_RATE 192
#define PF_FG 200
#define PF_A 208
#define PF_WBM 256
#define PF_WBA 264
#define PF_GM 272
#define PF_GA 280
#define PF_SM 288
#define PF_SA 296
#define PF_FM 304
#define PF_FA 312
#define PF_CM 320
#define PF_CA 328
#define PF_TM 336
#define PF_TA 344
#define PF_LINE 360   // 8 ints
#define PF_TCS 368    // tc[k]*tsc, 8*8
#define PF_TPRE 432   // prefix sums, 8*8
#define PF_IA 496     // 1/a, 24

// quantity indices for min/max pair arrays: q*64 + s (min), q*64+32+s (max), s=0..31
#define QX(b,c) ((b)*3+(c))
#define QS 24
#define QJ 25
#define QC 26
#define QFIN 27
#define SL_LCOUNT 1792
#define SL_BINSTAR 1920
#define SL_RNEED 1928
#define SL_SUMA2 2048   // float[24][32]

struct GK { float w[13]; };

__device__ __forceinline__ void waveFence(){ __builtin_amdgcn_wave_barrier(); }

__device__ __forceinline__ unsigned fkey(float f){
    unsigned u = __float_as_uint(f);
    return (u & 0x80000000u) ? ~u : (u | 0x80000000u);
}
__device__ __forceinline__ float funkey(unsigned k){
    return (k & 0x80000000u) ? __uint_as_float(k & 0x7FFFFFFFu) : __uint_as_float(~k);
}

__device__ __forceinline__ void blockRedPair(unsigned kmn, unsigned kmx, int q,
                                             unsigned* slots, unsigned* lds8){
    #pragma unroll
    for (int o = 32; o > 0; o >>= 1){
        kmn = min(kmn, __shfl_down(kmn, o));
        kmx = max(kmx, __shfl_down(kmx, o));
    }
    int w = threadIdx.x >> 6;
    if ((threadIdx.x & 63) == 0){ lds8[w] = kmn; lds8[4+w] = kmx; }
    __syncthreads();
    if (threadIdx.x == 0){
        unsigned mn = min(min(lds8[0],lds8[1]), min(lds8[2],lds8[3]));
        unsigned mx = max(max(lds8[4],lds8[5]), max(lds8[6],lds8[7]));
        int s = blockIdx.x & 31;
        atomicMin(&slots[q*64 + s], mn);
        atomicMax(&slots[q*64 + 32 + s], mx);
    }
    __syncthreads();
}

__device__ __forceinline__ float toneF(float v, const float* tc, float tsc){
    float tn = 0.f;
    #pragma unroll
    for (int i = 0; i < 8; ++i){
        float d = v - 0.125f * (float)i;
        d = fminf(fmaxf(d, 0.f), 0.125f);
        tn += d * tc[i];
    }
    return tn * tsc;
}

// ---------------- complex helpers + radix-8 Stockham FFT (512 = 8^3) ----------------
__device__ __forceinline__ float2 cadd(float2 a, float2 b){ return make_float2(a.x+b.x, a.y+b.y); }
__device__ __forceinline__ float2 csub(float2 a, float2 b){ return make_float2(a.x-b.x, a.y-b.y); }
__device__ __forceinline__ float2 cmul(float2 a, float2 b){ return make_float2(a.x*b.x - a.y*b.y, a.x*b.y + a.y*b.x); }

template<int S>   // S=-1 fwd, S=+1 inv
__device__ __forceinline__ float2 rot90(float2 z){
    return (S < 0) ? make_float2(z.y, -z.x) : make_float2(-z.y, z.x);
}

template<int S>
__device__ __forceinline__ void fft4p(float2 a, float2 b, float2 c, float2 d,
                                      float2& X0, float2& X1, float2& X2, float2& X3){
    float2 t0 = cadd(a,c), t1 = csub(a,c), t2 = cadd(b,d), t3 = csub(b,d);
    float2 it3 = rot90<S>(t3);
    X0 = cadd(t0,t2); X2 = csub(t0,t2);
    X1 = cadd(t1,it3); X3 = csub(t1,it3);
}

template<int S>
__device__ __forceinline__ void bfly8(float2 v[8]){
    const float C = 0.70710678118654752f;
    float2 E0,E1,E2,E3,O0,O1,O2,O3;
    fft4p<S>(v[0],v[2],v[4],v[6], E0,E1,E2,E3);
    fft4p<S>(v[1],v[3],v[5],v[7], O0,O1,O2,O3);
    float2 w1 = make_float2(C, (S<0) ? -C : C);
    float2 w3 = make_float2(-C, (S<0) ? -C : C);
    float2 u1 = cmul(O1, w1);
    float2 u2 = rot90<S>(O2);
    float2 u3 = cmul(O3, w3);
    v[0]=cadd(E0,O0); v[4]=csub(E0,O0);
    v[1]=cadd(E1,u1); v[5]=csub(E1,u1);
    v[2]=cadd(E2,u2); v[6]=csub(E2,u2);
    v[3]=cadd(E3,u3); v[7]=csub(E3,u3);
}

__device__ __forceinline__ void twiddles(float2 v[8], float th){
    float sn, cs; __sincosf(th, &sn, &cs);
    float2 w1 = make_float2(cs, sn);
    float2 w = w1;
    v[1] = cmul(v[1], w1);
    #pragma unroll
    for (int r = 2; r < 8; ++r){ w = cmul(w, w1); v[r] = cmul(v[r], w); }
}

// Stockham FFT, natural in/out: v[r] = elem(lane + 64r). buf PRIVATE to this wave.
template<int S>
__device__ __forceinline__ void fft512reg(float2 v[8], float2* buf, int lane){
    bfly8<S>(v);
    #pragma unroll
    for (int q = 0; q < 8; ++q) buf[PIDX(8*lane + q)] = v[q];
    waveFence();
    #pragma unroll
    for (int r = 0; r < 8; ++r) v[r] = buf[PIDX(lane + 64*r)];
    waveFence();
    twiddles(v, (float)S * 6.2831853072f * (float)(lane & 7) * (1.0f/64.0f));
    bfly8<S>(v);
    {
        int basei = ((lane >> 3) << 6) + (lane & 7);
        #pragma unroll
        for (int q = 0; q < 8; ++q) buf[PIDX(basei + 8*q)] = v[q];
    }
    waveFence();
    #pragma unroll
    for (int r = 0; r < 8; ++r) v[r] = buf[PIDX(lane + 64*r)];
    waveFence();
    twiddles(v, (float)S * 6.2831853072f * (float)lane * (1.0f/512.0f));
    bfly8<S>(v);
}

// ---------------- setup ----------------
__global__ __launch_bounds__(256) void kSetup(
    const float* __restrict__ lat,
    const float* gw, const float* gb, const float* wbw, const float* wbb,
    const float* gaw, const float* gab, const float* shw, const float* shb,
    const float* dfw, const float* dfb, const float* ctw, const float* ctb,
    const float* tow, const float* tob, const float* ffw, const float* ffb,
    float* P, unsigned* slots, unsigned* hist)
{
    if (blockIdx.x != 0){
        int i = (blockIdx.x - 1) * 256 + threadIdx.x;
        if (i < 4096) slots[i] = (i < 1792 && (i & 63) < 32) ? 0xFFFFFFFFu : 0u;
        if (i < 8192) hist[i] = 0u;
        return;
    }
    int t = threadIdx.x;
    if (t < 192){
        int b = t / 24, o = t % 24;
        const float* L = lat + b * 256;
        const float* W; float bias; int nc, col;
        if (o < 8)      { W=gw;  bias=gb[o];     nc=8; col=o;    }
        else if (o < 11){ W=wbw; bias=wbb[o-8];  nc=3; col=o-8;  }
        else if (o==11) { W=gaw; bias=gab[0];    nc=1; col=0;    }
        else if (o==12) { W=shw; bias=shb[0];    nc=1; col=0;    }
        else if (o==13) { W=dfw; bias=dfb[0];    nc=1; col=0;    }
        else if (o==14) { W=ctw; bias=ctb[0];    nc=1; col=0;    }
        else if (o<23)  { W=tow; bias=tob[o-15]; nc=8; col=o-15; }
        else            { W=ffw; bias=ffb[0];    nc=1; col=0;    }
        float acc = bias;
        for (int d = 0; d < 256; ++d) acc += L[d] * W[d*nc + col];
        float t01 = tanhf(acc) * 0.5f + 0.5f;
        if (o < 8){ float v = t01*0.99f + 0.01f; P[PF_GATE + b*8 + o] = v; if (o==7) P[PF_FG + b] = v; }
        else if (o < 11){ P[PF_WB + b*3 + (o-8)] = expf(t01 - 0.5f); }
        else if (o==11){ float lg = logf(2.5f); P[PF_GAMMA + b] = expf(t01*(2.f*lg) - lg); }
        else if (o==12){ P[PF_Y + b] = t01*0.9f + 0.1f; }
        else if (o==13){ P[PF_OMEGA + b] = t01*0.9f + 0.1f; }
        else if (o==14){ P[PF_ALPHA + b] = tanhf(acc); }
        else if (o<23){ P[PF_TC + b*8 + (o-15)] = t01*1.5f + 0.5f; }
        else { P[PF_RATE + b] = t01*0.7f + 0.1f; }
    }
    __syncthreads();
    if (t < 8){
        int b = t;
        float w0=P[PF_WB+b*3], w1=P[PF_WB+b*3+1], w2=P[PF_WB+b*3+2];
        float cs = 1.0f / (1e-5f + 0.27f*w0 + 0.67f*w1 + 0.06f*w2);
        P[PF_WB+b*3] = cs*w0; P[PF_WB+b*3+1] = cs*w1; P[PF_WB+b*3+2] = cs*w2;
        float ts = 0.f;
        for (int i = 0; i < 8; ++i) ts += P[PF_TC + b*8 + i];
        float tsc = 8.0f / (ts + 1e-30f);
        P[PF_TSC + b] = tsc;
        float acc = 0.f;
        for (int k = 0; k < 8; ++k){
            float tck = P[PF_TC + b*8 + k] * tsc;
            P[PF_TCS + b*8 + k] = tck;
            P[PF_TPRE + b*8 + k] = acc;
            acc += tck * 0.125f;
        }
        int bs = (b + 4) & 7; // fftshift batch roll
        ((int*)(P + PF_LINE))[b] = (int)floorf(sqrtf(262144.0f * P[PF_RATE + bs]) * 0.5f);
    }
}

// ---------------- FUSED: row FFT (2048 blocks) || x min/max + dark histogram (1024 blocks) ----------------
__global__ __launch_bounds__(256) void kHistRowFwd(const float* __restrict__ x, float2* __restrict__ bc,
                                                   unsigned* slots, unsigned* hist){
    __shared__ float2 buf4[4][580];
    __shared__ unsigned lds8[8];
    int t = threadIdx.x;
    if (blockIdx.x < 2048){
        // ---- forward row FFT (ch0+i*ch1 packed, ch2), row pair per block ----
        float (*xs)[3][512] = reinterpret_cast<float(*)[3][512]>(&buf4[0][0]);
        int b = blockIdx.x >> 8;
        int rp = blockIdx.x & 255;
        #pragma unroll
        for (int k = 0; k < 3; ++k){
            int l = t + (k << 8);
            int seg = l >> 7;
            int idx = (l & 127) << 2;
            int ch = seg >> 1, rr = seg & 1;
            float4 z = *(const float4*)(x + (size_t)(3*b + ch)*HW + ((size_t)(2*rp + rr) << 9) + idx);
            *(float4*)&xs[rr][ch][idx] = z;
        }
        __syncthreads();
        int u = t >> 6, lane = t & 63;
        int frr = u >> 1, pk = u & 1;
        float2 v[8];
        #pragma unroll
        for (int r = 0; r < 8; ++r){
            int i = lane + 64*r;
            if (pk == 0) v[r] = make_float2(xs[frr][0][i] * (1.0f/512.0f), xs[frr][1][i] * (1.0f/512.0f));
            else         v[r] = make_float2(xs[frr][2][i] * (1.0f/512.0f), 0.f);
        }
        __syncthreads();   // xs reads done before buf overwrites (cross-wave alias)
        fft512reg<-1>(v, buf4[u], lane);
        size_t ob = (size_t)(2*b + pk)*HW + ((size_t)(2*rp + frr) << 9);
        #pragma unroll
        for (int q = 0; q < 8; ++q) bc[ob + lane + 64*q] = v[q];
    } else {
        // ---- min/max + histogram ----
        unsigned* h = (unsigned*)&buf4[0][0];
        int hb = blockIdx.x - 2048;
        int b = hb >> 7;
        int blk = hb & 127;
        for (int i = t; i < NBIN; i += 256) h[i] = 0u;
        __syncthreads();
        size_t xb = (size_t)b*3*HW;
        int p0 = (((blk<<1)    )*256 + t) << 2;
        int p1 = (((blk<<1) + 1)*256 + t) << 2;
        float4 u0 = *(const float4*)(x + xb + p0);
        float4 u1 = *(const float4*)(x + xb + HW + p0);
        float4 u2 = *(const float4*)(x + xb + 2*HW + p0);
        float4 w0 = *(const float4*)(x + xb + p1);
        float4 w1 = *(const float4*)(x + xb + HW + p1);
        float4 w2 = *(const float4*)(x + xb + 2*HW + p1);
        float a0[8] = {u0.x,u0.y,u0.z,u0.w, w0.x,w0.y,w0.z,w0.w};
        float a1[8] = {u1.x,u1.y,u1.z,u1.w, w1.x,w1.y,w1.z,w1.w};
        float a2[8] = {u2.x,u2.y,u2.z,u2.w, w2.x,w2.y,w2.z,w2.w};
        float mn0=1e30f,mx0=-1e30f,mn1=1e30f,mx1=-1e30f,mn2=1e30f,mx2=-1e30f;
        #pragma unroll
        for (int e = 0; e < 8; ++e){
            float dark = fminf(a0[e], fminf(a1[e], a2[e]));
            atomicAdd(&h[min(NBIN-1, (int)(dark * (float)NBIN))], 1u);
            mn0 = fminf(mn0, a0[e]); mx0 = fmaxf(mx0, a0[e]);
            mn1 = fminf(mn1, a1[e]); mx1 = fmaxf(mx1, a1[e]);
            mn2 = fminf(mn2, a2[e]); mx2 = fmaxf(mx2, a2[e]);
        }
        __syncthreads();
        for (int i = t; i < NBIN; i += 256){
            unsigned c = h[i];
            if (c) atomicAdd(&hist[b*NBIN + i], c);
        }
        blockRedPair(fkey(mn0), fkey(mx0), QX(b,0), slots, lds8);
        blockRedPair(fkey(mn1), fkey(mx1), QX(b,1), slots, lds8);
        blockRedPair(fkey(mn2), fkey(mx2), QX(b,2), slots, lds8);
    }
}

// ---------------- descending scan of histogram -> threshold bin ----------------
__global__ __launch_bounds__(256) void kScanHist(const unsigned* __restrict__ hist, unsigned* slots){
    int b = blockIdx.x, t = threadIdx.x;
    __shared__ unsigned wtot[4];
    __shared__ int doneS;
    if (t == 0) doneS = 0;
    __syncthreads();
    unsigned total = 0;
    for (int c0 = 0; c0 < NBIN; c0 += 256){
        int binIdx = NBIN-1 - (c0 + t);
        unsigned cnt = hist[b*NBIN + binIdx];
        unsigned v = cnt;
        #pragma unroll
        for (int off = 1; off < 64; off <<= 1){
            unsigned u = __shfl_up(v, off);
            if ((t & 63) >= off) v += u;
        }
        if ((t & 63) == 63) wtot[t >> 6] = v;
        __syncthreads();
        unsigned wofs = 0;
        for (int w = 0; w < (t >> 6); ++w) wofs += wtot[w];
        unsigned incl = total + wofs + v;
        unsigned excl = incl - cnt;
        if (incl >= 261u && excl < 261u){
            slots[SL_BINSTAR + b] = (unsigned)binIdx;
            slots[SL_RNEED + b]   = 261u - excl;
            doneS = 1;
        }
        __syncthreads();
        if (doneS) break;
        total += wtot[0] + wtot[1] + wtot[2] + wtot[3];
        __syncthreads();
    }
}

// ---------------- FUSED: FFT col pass (1024) || collect (2048) || blur (1536) ----------------
__global__ __launch_bounds__(256) void kCCB(const float* __restrict__ x, float2* __restrict__ bc,
                                            const int* __restrict__ lineS, unsigned* slots, uint2* list,
                                            const float* __restrict__ P, float* __restrict__ sharpOut, GK gk){
    __shared__ __align__(16) char smem[45056];
    int t = threadIdx.x;
    if (blockIdx.x < 1024){
        // ---- column FFT: 8-col tile, fwd + mask + inv ----
        int img  = blockIdx.x >> 6;
        int tile = blockIdx.x & 63;
        int c0 = tile << 3;
        int line = lineS[img >> 1];
        if (c0 >= line && c0 + 8 <= 512 - line) return;
        float2 (*cb)[580] = reinterpret_cast<float2(*)[580]>(smem);
        size_t ibase = (size_t)img*HW + c0;
        for (int k = 0; k < 16; ++k){
            int idx = (k << 8) + t;
            int row = idx >> 3, col = idx & 7;
            float2 z = bc[ibase + ((size_t)row << 9) + col];
            cb[col][PIDX(row)] = make_float2(z.x * (1.0f/512.0f), z.y * (1.0f/512.0f));
        }
        __syncthreads();
        int lane = t & 63, u = t >> 6;
        #pragma unroll
        for (int h = 0; h < 2; ++h){
            int col = (h << 2) + u;
            int cc = c0 + col;
            bool colM = (cc < line) || (cc >= 512 - line);
            float2 v[8];
            #pragma unroll
            for (int r = 0; r < 8; ++r) v[r] = cb[col][PIDX(lane + 64*r)];
            waveFence();
            fft512reg<-1>(v, cb[col], lane);
            if (colM){
                #pragma unroll
                for (int q = 0; q < 8; ++q){
                    int f = lane + (q << 6);
                    if (f < line || f >= 512 - line) v[q] = make_float2(0.f, 0.f);
                }
            }
            waveFence();
            fft512reg<+1>(v, cb[col], lane);
            #pragma unroll
            for (int q = 0; q < 8; ++q) cb[col][PIDX(lane + 64*q)] = v[q];
            waveFence();
        }
        __syncthreads();
        for (int k = 0; k < 16; ++k){
            int idx = (k << 8) + t;
            int row = idx >> 3, col = idx & 7;
            int cc = c0 + col;
            if (cc < line || cc >= 512 - line)
                bc[ibase + ((size_t)row << 9) + col] = cb[col][PIDX(row)];
        }
    } else if (blockIdx.x < 3072){
        // ---- collect: block-reduced above-threshold sums + boundary list ----
        float (*wsum)[4] = reinterpret_cast<float(*)[4]>(smem);
        int cbk = blockIdx.x - 1024;
        int b = cbk >> 8;
        int tile = cbk & 255;
        size_t xb = (size_t)b*3*HW;
        int p = (tile*256 + t) << 2;
        float4 v0 = *(const float4*)(x + xb + p);
        float4 v1 = *(const float4*)(x + xb + HW + p);
        float4 v2 = *(const float4*)(x + xb + 2*HW + p);
        int bs = (int)slots[SL_BINSTAR + b];
        float a0[4] = {v0.x,v0.y,v0.z,v0.w};
        float a1[4] = {v1.x,v1.y,v1.z,v1.w};
        float a2[4] = {v2.x,v2.y,v2.z,v2.w};
        float s0 = 0.f, s1 = 0.f, s2 = 0.f;
        #pragma unroll
        for (int e = 0; e < 4; ++e){
            float dark = fminf(a0[e], fminf(a1[e], a2[e]));
            int bin = min(NBIN-1, (int)(dark * (float)NBIN));
            if (bin > bs){ s0 += a0[e]; s1 += a1[e]; s2 += a2[e]; }
            else if (bin == bs){
                unsigned n = atomicAdd(&slots[SL_LCOUNT + b], 1u);
                if (n < 1024u) list[(b << 10) + n] = make_uint2(__float_as_uint(dark), (unsigned)(p + e));
            }
        }
        #pragma unroll
        for (int o = 32; o > 0; o >>= 1){
            s0 += __shfl_down(s0, o); s1 += __shfl_down(s1, o); s2 += __shfl_down(s2, o);
        }
        int w = t >> 6;
        if ((t & 63) == 0){ wsum[0][w] = s0; wsum[1][w] = s1; wsum[2][w] = s2; }
        __syncthreads();
        if (t == 0){
            float t0 = wsum[0][0]+wsum[0][1]+wsum[0][2]+wsum[0][3];
            float t1 = wsum[1][0]+wsum[1][1]+wsum[1][2]+wsum[1][3];
            float t2 = wsum[2][0]+wsum[2][1]+wsum[2][2]+wsum[2][3];
            float* F = (float*)(slots + SL_SUMA2);
            int sl = blockIdx.x & 31;
            atomicAdd(&F[(b*3+0)*32 + sl], t0);
            atomicAdd(&F[(b*3+1)*32 + sl], t1);
            atomicAdd(&F[(b*3+2)*32 + sl], t2);
        }
    } else {
        // ---- blur: separable gaussian, stores sharpened s = x + y*(x-blur) ----
        float (*tile)[80] = reinterpret_cast<float(*)[80]>(smem);
        float (*hbuf)[68] = reinterpret_cast<float(*)[68]>(smem + 24320);
        unsigned* lds8 = reinterpret_cast<unsigned*>(smem + 44992);
        int bb = blockIdx.x - 3072;
        int img = bb >> 6;
        int tid = bb & 63;
        int tr0 = (tid >> 3) << 6;
        int tc0 = (tid & 7) << 6;
        size_t ib = (size_t)img * HW;
        for (int l = t; l < 76*76; l += 256){
            int r = l / 76, c = l - r*76;
            int gr = tr0 + r - 6; gr = (gr < 0) ? -gr : ((gr > 511) ? 1022 - gr : gr);
            int gc = tc0 + c - 6; gc = (gc < 0) ? -gc : ((gc > 511) ? 1022 - gc : gc);
            tile[r][c] = x[ib + ((size_t)gr << 9) + gc];
        }
        __syncthreads();
        for (int l = t; l < 76*64; l += 256){
            int r = l >> 6, c = l & 63;
            float acc = 0.f;
            #pragma unroll
            for (int k = 0; k < 13; ++k) acc += gk.w[k] * tile[r][c + k];
            hbuf[r][c] = acc;
        }
        __syncthreads();
        float yb = P[PF_Y + img/3];
        unsigned kmn = 0xFFFFFFFFu, kmx = 0u;
        for (int l = t; l < 64*64; l += 256){
            int r = l >> 6, c = l & 63;
            float acc = 0.f;
            #pragma unroll
            for (int k = 0; k < 13; ++k) acc += gk.w[k] * hbuf[r + k][c];
            float xv = tile[r + 6][c + 6];
            float s = xv + yb * (xv - acc);
            sharpOut[ib + ((size_t)(tr0 + r) << 9) + tc0 + c] = s;
            unsigned key = fkey(s);
            kmn = min(kmn, key); kmx = max(kmx, key);
        }
        blockRedPair(kmn, kmx, QS, slots, lds8);
    }
}

// ---------------- finish atmospheric light: wave-parallel top-r selection ----------------
__global__ void kSelect(const float* __restrict__ x, uint2* list, unsigned* slots, float* P){
    __shared__ unsigned pid[262];
    __shared__ char taken[1024];
    int b = blockIdx.x, t = threadIdx.x;  // 64 threads
    int n = (int)min(slots[SL_LCOUNT + b], 1024u);
    int r = (int)slots[SL_RNEED + b];
    if (r > n) r = n;
    const uint2* L = &list[b << 10];
    for (int i = t; i < n; i += 64) taken[i] = 0;
    __syncthreads();
    for (int it = 0; it < r; ++it){
        unsigned long long bk = 0ull; int bp = -1;
        for (int i = t; i < n; i += 64){
            if (taken[i]) continue;
            uint2 e = L[i];
            unsigned long long key = ((unsigned long long)e.x << 32) | e.y;
            if (key > bk){ bk = key; bp = i; }
        }
        #pragma unroll
        for (int o = 32; o > 0; o >>= 1){
            unsigned long long ok = __shfl_down(bk, o);
            int op = __shfl_down(bp, o);
            if (ok > bk){ bk = ok; bp = op; }
        }
        bp = __shfl(bp, 0);
        if (t == 0){ pid[it] = L[bp].y; taken[bp] = 1; }
        __syncthreads();
    }
    float s0 = 0.f, s1 = 0.f, s2 = 0.f;
    size_t xb = (size_t)b*3*HW;
    for (int i = t; i < r; i += 64){
        unsigned id = pid[i];
        s0 += x[xb + id]; s1 += x[xb + HW + id]; s2 += x[xb + 2*HW + id];
    }
    #pragma unroll
    for (int o = 32; o > 0; o >>= 1){
        s0 += __shfl_down(s0, o); s1 += __shfl_down(s1, o); s2 += __shfl_down(s2, o);
    }
    if (t == 0){
        const float* F = (const float*)(slots + SL_SUMA2);
        float f0 = 0.f, f1 = 0.f, f2 = 0.f;
        for (int k = 0; k < 32; ++k){
            f0 += F[(b*3+0)*32 + k];
            f1 += F[(b*3+1)*32 + k];
            f2 += F[(b*3+2)*32 + k];
        }
        float A0 = (s0 + f0) / 262.0f, A1 = (s1 + f1) / 262.0f, A2 = (s2 + f2) / 262.0f;
        P[PF_A + b*3+0] = A0; P[PF_A + b*3+1] = A1; P[PF_A + b*3+2] = A2;
        P[PF_IA + b*3+0] = 1.0f/A0; P[PF_IA + b*3+1] = 1.0f/A1; P[PF_IA + b*3+2] = 1.0f/A2;
    }
}

// ---------------- fog(j) & contrast(cimg) global min/max (2048 blocks) ----------------
__global__ __launch_bounds__(256) void kJCMinmax(const float* __restrict__ x, const float* __restrict__ P, unsigned* slots){
    __shared__ unsigned lds8[8];
    int b = blockIdx.x >> 8;
    int tile = blockIdx.x & 255;
    size_t xb = (size_t)b*3*HW;
    int p = (tile*256 + threadIdx.x) << 2;
    float4 v0 = *(const float4*)(x + xb + p);
    float4 v1 = *(const float4*)(x + xb + HW + p);
    float4 v2 = *(const float4*)(x + xb + 2*HW + p);
    float ia0 = P[PF_IA+b*3], ia1 = P[PF_IA+b*3+1], ia2 = P[PF_IA+b*3+2];
    float a0 = P[PF_A+b*3],  a1 = P[PF_A+b*3+1],  a2 = P[PF_A+b*3+2];
    float om = P[PF_OMEGA+b], al = P[PF_ALPHA+b];
    float a0v[4] = {v0.x,v0.y,v0.z,v0.w};
    float a1v[4] = {v1.x,v1.y,v1.z,v1.w};
    float a2v[4] = {v2.x,v2.y,v2.z,v2.w};
    float jmn = 1e30f, jmx = -1e30f, cmn = 1e30f, cmx = -1e30f;
    #pragma unroll
    for (int e = 0; e < 4; ++e){
        float x0 = a0v[e], x1 = a1v[e], x2 = a2v[e];
        float dr = fminf(x0*ia0, fminf(x1*ia1, x2*ia2));
        float T = fmaxf(1.0f - om*dr, 0.01f);
        float rT = 1.0f / T;
        float j0 = (x0-a0)*rT + a0, j1 = (x1-a1)*rT + a1, j2 = (x2-a2)*rT + a2;
        float lum = fminf(fmaxf(0.27f*x0 + 0.67f*x1 + 0.06f*x2, 0.f), 1.f);
        float clum = -__cosf(PI_F*lum)*0.5f + 0.5f;
        float alx = (1.f - al) + al * (clum / (lum + 1e-6f));
        float c0 = x0*alx, c1 = x1*alx, c2 = x2*alx;
        jmn = fminf(jmn, fminf(j0, fminf(j1, j2))); jmx = fmaxf(jmx, fmaxf(j0, fmaxf(j1, j2)));
        cmn = fminf(cmn, fminf(c0, fminf(c1, c2))); cmx = fmaxf(cmx, fmaxf(c0, fmaxf(c1, c2)));
    }
    blockRedPair(fkey(jmn), fkey(jmx), QJ, slots, lds8);
    blockRedPair(fkey(cmn), fkey(cmx), QC, slots, lds8);
}

// ---------------- normalization params ----------------
__global__ void kNormParams(float* P, const unsigned* __restrict__ slots){
    __shared__ float mnv[28], mxv[28];
    int t = threadIdx.x;
    if (t < 28){
        unsigned kmn = 0xFFFFFFFFu, kmx = 0u;
        for (int s = 0; s < 32; ++s){
            kmn = min(kmn, slots[t*64 + s]);
            kmx = max(kmx, slots[t*64 + 32 + s]);
        }
        mnv[t] = funkey(kmn); mxv[t] = funkey(kmx);
    }
    __syncthreads();
    if (t == 0){
        float wmin=1e30f, wmax=-1e30f, gmin=1e30f, gmax=-1e30f, tmin=1e30f, tmax=-1e30f;
        for (int b = 0; b < 8; ++b){
            float gam = P[PF_GAMMA+b];
            float tsc = P[PF_TSC+b];
            const float* tc = &P[PF_TC + b*8];
            float xbmin = 1e30f, xbmax = -1e30f;
            for (int c = 0; c < 3; ++c){
                int i = b*3 + c;
                float w = P[PF_WB + i];
                wmin = fminf(wmin, w * mnv[i]); wmax = fmaxf(wmax, w * mxv[i]);
                gmin = fminf(gmin, __powf(fmaxf(mnv[i], 1e-4f), gam));
                gmax = fmaxf(gmax, __powf(fmaxf(mxv[i], 1e-4f), gam));
                xbmin = fminf(xbmin, mnv[i]); xbmax = fmaxf(xbmax, mxv[i]);
            }
            tmin = fminf(tmin, toneF(xbmin, tc, tsc));
            tmax = fmaxf(tmax, toneF(xbmax, tc, tsc));
        }
        float smin = mnv[QS], smax = mxv[QS];
        float jmin = mnv[QJ], jmax = mxv[QJ];
        float cmin = mnv[QC], cmax = mxv[QC];
        for (int b = 0; b < 8; ++b){
            const float* G = &P[PF_GATE + b*8];
            float m;
            m = G[0]/(wmax-wmin); P[PF_WBM+b]=m; P[PF_WBA+b]=-wmin*m;
            m = G[1]/(gmax-gmin); P[PF_GM +b]=m; P[PF_GA +b]=-gmin*m;
            m = G[3]/(smax-smin); P[PF_SM +b]=m; P[PF_SA +b]=-smin*m;
            m = G[4]/(jmax-jmin); P[PF_FM +b]=m; P[PF_FA +b]=-jmin*m;
            m = G[5]/(cmax-cmin); P[PF_CM +b]=m; P[PF_CA +b]=-cmin*m;
            m = G[6]/(tmax-tmin); P[PF_TM +b]=m; P[PF_TA +b]=-tmin*m;
        }
    }
}

// ---------------- fused: inverse row FFT (packed) on row pair + combine ----------------
__global__ __launch_bounds__(256) void kCombineFFT(const float* __restrict__ x, float* __restrict__ outb,
                                                   const float2* __restrict__ bc, const float* __restrict__ P,
                                                   unsigned* slots){
    __shared__ float2 buf4[4][580];
    __shared__ float stc[8], spre[8];
    __shared__ unsigned lds8[8];
    float (*fbuf)[3][512] = reinterpret_cast<float(*)[3][512]>(&buf4[0][0]);
    int b = blockIdx.x >> 8;
    int rp = blockIdx.x & 255;
    int t = threadIdx.x;
    if (t < 8){ stc[t] = P[PF_TCS + b*8 + t]; spre[t] = P[PF_TPRE + b*8 + t]; }
    int u = t >> 6, lane = t & 63;
    int frr = u >> 1, pk = u & 1;
    float2 v[8];
    size_t ib = (size_t)(2*b + pk)*HW + ((size_t)(2*rp + frr) << 9);
    #pragma unroll
    for (int r = 0; r < 8; ++r) v[r] = bc[ib + lane + 64*r];
    fft512reg<+1>(v, buf4[u], lane);
    __syncthreads();
    if (pk == 0){
        #pragma unroll
        for (int q = 0; q < 8; ++q){
            int i = lane + 64*q;
            fbuf[frr][0][i] = fabsf(v[q].x);
            fbuf[frr][1][i] = fabsf(v[q].y);
        }
    } else {
        #pragma unroll
        for (int q = 0; q < 8; ++q) fbuf[frr][2][lane + 64*q] = fabsf(v[q].x);
    }
    __syncthreads();

    float g  = P[PF_FG + b];
    float wb0=P[PF_WB+b*3], wb1=P[PF_WB+b*3+1], wb2=P[PF_WB+b*3+2];
    float gam=P[PF_GAMMA+b], om=P[PF_OMEGA+b], al=P[PF_ALPHA+b];
    float a0=P[PF_A+b*3], a1=P[PF_A+b*3+1], a2=P[PF_A+b*3+2];
    float ia0=P[PF_IA+b*3], ia1=P[PF_IA+b*3+1], ia2=P[PF_IA+b*3+2];
    float g2=P[PF_GATE+b*8+2];
    float wbm=P[PF_WBM+b], wba=P[PF_WBA+b], gm=P[PF_GM+b], ga=P[PF_GA+b];
    float sm=P[PF_SM+b], sa=P[PF_SA+b], fm=P[PF_FM+b], fa=P[PF_FA+b];
    float cm=P[PF_CM+b], ca=P[PF_CA+b], tm=P[PF_TM+b], ta=P[PF_TA+b];
    float kadd = wba + ga + sa + fa + ca + ta;
    float cw0 = wb0*wbm + g2, cw1 = wb1*wbm + g2, cw2 = wb2*wbm + g2;

    int rr = t >> 7, c4 = (t & 127) << 2;
    size_t p0 = (size_t)(3*b)*HW + ((size_t)(2*rp + rr) << 9) + c4;
    float4 xv0 = *(const float4*)(x + p0);
    float4 xv1 = *(const float4*)(x + p0 + HW);
    float4 xv2 = *(const float4*)(x + p0 + 2*HW);
    float4 sv0 = *(const float4*)(outb + p0);
    float4 sv1 = *(const float4*)(outb + p0 + HW);
    float4 sv2 = *(const float4*)(outb + p0 + 2*HW);
    float4 fv0 = *(float4*)&fbuf[rr][0][c4];
    float4 fv1 = *(float4*)&fbuf[rr][1][c4];
    float4 fv2 = *(float4*)&fbuf[rr][2][c4];
    float X0[4]={xv0.x,xv0.y,xv0.z,xv0.w}, X1[4]={xv1.x,xv1.y,xv1.z,xv1.w}, X2[4]={xv2.x,xv2.y,xv2.z,xv2.w};
    float S0[4]={sv0.x,sv0.y,sv0.z,sv0.w}, S1[4]={sv1.x,sv1.y,sv1.z,sv1.w}, S2[4]={sv2.x,sv2.y,sv2.z,sv2.w};
    float F0[4]={fv0.x,fv0.y,fv0.z,fv0.w}, F1[4]={fv1.x,fv1.y,fv1.z,fv1.w}, F2[4]={fv2.x,fv2.y,fv2.z,fv2.w};
    float O0[4], O1[4], O2[4];
    float mn = 1e30f, mx = -1e30f;
    #pragma unroll
    for (int e = 0; e < 4; ++e){
        float x0 = X0[e], x1 = X1[e], x2 = X2[e];
        float dr = fminf(x0*ia0, fminf(x1*ia1, x2*ia2));
        float T = fmaxf(1.0f - om*dr, 0.01f);
        float rT = 1.0f / T;
        float lum = fminf(fmaxf(0.27f*x0 + 0.67f*x1 + 0.06f*x2, 0.f), 1.f);
        float clum = -__cosf(PI_F*lum)*0.5f + 0.5f;
        float alx = (1.f - al) + al * (clum / (lum + 1e-6f));
        {
            float j = (x0 - a0)*rT + a0;
            int k = min(7, (int)(x0 * 8.0f));
            float tn = spre[k] + (x0 - 0.125f*(float)k) * stc[k];
            float gp = __powf(fmaxf(x0, 1e-4f), gam);
            float sum = x0*cw0 + gp*gm + S0[e]*sm + j*fm + (x0*alx)*cm + tn*tm + kadd + F0[e]*g;
            O0[e] = sum; mn = fminf(mn, sum); mx = fmaxf(mx, sum);
        }
        {
            float j = (x1 - a1)*rT + a1;
            int k = min(7, (int)(x1 * 8.0f));
            float tn = spre[k] + (x1 - 0.125f*(float)k) * stc[k];
            float gp = __powf(fmaxf(x1, 1e-4f), gam);
            float sum = x1*cw1 + gp*gm + S1[e]*sm + j*fm + (x1*alx)*cm + tn*tm + kadd + F1[e]*g;
            O1[e] = sum; mn = fminf(mn, sum); mx = fmaxf(mx, sum);
        }
        {
            float j = (x2 - a2)*rT + a2;
            int k = min(7, (int)(x2 * 8.0f));
            float tn = spre[k] + (x2 - 0.125f*(float)k) * stc[k];
            float gp = __powf(fmaxf(x2, 1e-4f), gam);
            float sum = x2*cw2 + gp*gm + S2[e]*sm + j*fm + (x2*alx)*cm + tn*tm + kadd + F2[e]*g;
            O2[e] = sum; mn = fminf(mn, sum); mx = fmaxf(mx, sum);
        }
    }
    *(float4*)(outb + p0)        = make_float4(O0[0],O0[1],O0[2],O0[3]);
    *(float4*)(outb + p0 + HW)   = make_float4(O1[0],O1[1],O1[2],O1[3]);
    *(float4*)(outb + p0 + 2*HW) = make_float4(O2[0],O2[1],O2[2],O2[3]);
    blockRedPair(fkey(mn), fkey(mx), QFIN, slots, lds8);
}

__global__ __launch_bounds__(256) void kFinalNorm(float* __restrict__ out, const unsigned* __restrict__ slots){
    unsigned kmn = 0xFFFFFFFFu, kmx = 0u;
    for (int s = 0; s < 32; ++s){
        kmn = min(kmn, slots[QFIN*64 + s]);
        kmx = max(kmx, slots[QFIN*64 + 32 + s]);
    }
    float mn = funkey(kmn), mx = funkey(kmx);
    float inv = 1.0f / (mx - mn);
    size_t i = ((size_t)blockIdx.x*256 + threadIdx.x) << 2;
    float4 v = *(const float4*)(out + i);
    v.x = (v.x - mn) * inv; v.y = (v.y - mn) * inv;
    v.z = (v.z - mn) * inv; v.w = (v.w - mn) * inv;
    *(float4*)(out + i) = v;
}

extern "C" void kernel_launch(void* const* d_in, const int* in_sizes, int n_in,
                              void* d_out, int out_size, void* d_ws, size_t ws_size,
                              hipStream_t stream){
    const float* x   = (const float*)d_in[0];
    const float* lat = (const float*)d_in[1];
    const float* gw  = (const float*)d_in[2];  const float* gb  = (const float*)d_in[3];
    const float* wbw = (const float*)d_in[4];  const float* wbb = (const float*)d_in[5];
    const float* gaw = (const float*)d_in[6];  const float* gab = (const float*)d_in[7];
    const float* shw = (const float*)d_in[8];  const float* shb = (const float*)d_in[9];
    const float* dfw = (const float*)d_in[10]; const float* dfb = (const float*)d_in[11];
    const float* ctw = (const float*)d_in[12]; const float* ctb = (const float*)d_in[13];
    const float* tow = (const float*)d_in[14]; const float* tob = (const float*)d_in[15];
    const float* ffw = (const float*)d_in[16]; const float* ffb = (const float*)d_in[17];
    float* out = (float*)d_out;
    char* ws = (char*)d_ws;

    float*    P     = (float*)ws;
    unsigned* slots = (unsigned*)(ws + 4096);
    unsigned* hist  = (unsigned*)(ws + 20480);
    uint2*    list  = (uint2*)(ws + 540672);
    float2*   bufC  = (float2*)(ws + 1048576);
    const int* lineS = (const int*)(P + PF_LINE);

    GK gk;
    {
        float s = 0.f;
        for (int i = 0; i < 13; ++i){ float t = (float)i - 6.f; gk.w[i] = expf(-(t*t)/8.0f); s += gk.w[i]; }
        for (int i = 0; i < 13; ++i) gk.w[i] /= s;
    }

    hipLaunchKernelGGL(kSetup,       dim3(41),   dim3(256), 0, stream, lat, gw,gb,wbw,wbb,gaw,gab,shw,shb,dfw,dfb,ctw,ctb,tow,tob,ffw,ffb, P, slots, hist);
    hipLaunchKernelGGL(kHistRowFwd,  dim3(3072), dim3(256), 0, stream, x, bufC, slots, hist);
    hipLaunchKernelGGL(kScanHist,    dim3(8),    dim3(256), 0, stream, hist, slots);
    hipLaunchKernelGGL(kCCB,         dim3(4608), dim3(256), 0, stream, x, bufC, lineS, slots, list, P, out, gk);
    hipLaunchKernelGGL(kSelect,      dim3(8),    dim3(64),  0, stream, x, list, slots, P);
    hipLaunchKernelGGL(kJCMinmax,    dim3(2048), dim3(256), 0, stream, x, P, slots);
    hipLaunchKernelGGL(kNormParams,  dim3(1),    dim3(64),  0, stream, P, slots);
    hipLaunchKernelGGL(kCombineFFT,  dim3(2048), dim3(256), 0, stream, x, out, bufC, P, slots);
    hipLaunchKernelGGL(kFinalNorm,   dim3(6144), dim3(256), 0, stream, out, slots);
}